// Round 10
// baseline (5880.591 us; speedup 1.0000x reference)
//
#include <hip/hip_runtime.h>
#include <hip/hip_cooperative_groups.h>
#include <cstdint>
#include <cstddef>

namespace cg = cooperative_groups;

#define NN 5000     // nodes per batch block
#define EE 40000    // edges per batch block
#define BATCH 8
#define SS 12
#define FF 16
#define HH 128
#define TOTAL 40000 // BATCH*NN
#define CC 4
#define NTILES (TOTAL / 32)   // 1250

// Layout: per-row state arrays use row = n*8 + bb (batch-interleaved). Gather-only
// message matrices are INT8 with one fp32 scale per source node per matrix.
//
// R10: PERSISTENT COOPERATIVE LOOP. The 48 dependent dispatches (12 steps x
// {B cand0, C gates1, D cand1, E gates0/final}) become ONE cooperative kernel
// with grid.sync() between phases (grid-stride over 1250 tiles). Removes
// 48x (launch + ramp + 226-block tail) overhead that R9's counters isolated
// (29us/dispatch vs ~10us traffic floor; HBM 20%, MFMA 4% -> not HW-bound).
// Phase bodies are byte-identical to R9's kernels. Fallback: if cooperative
// launch errors, run the R9 multi-kernel loop (same math).
//
// CORRECTNESS (G16): phase ordering via grid.sync (device-scope fence inside);
// each phase reads only buffers completed before the preceding sync. Cq is
// dedicated (not aliasing GqR) — R2's race lesson.

typedef __attribute__((ext_vector_type(8))) short short8;   // 8 bf16 (4 VGPRs)
typedef __attribute__((ext_vector_type(4))) float f32x4;    // 4 fp32

__device__ __forceinline__ unsigned short f2bf(float f) {
  union { float f; unsigned u; } v; v.f = f;
  unsigned r = v.u + 0x7fff + ((v.u >> 16) & 1);  // RTNE
  return (unsigned short)(r >> 16);
}
__device__ __forceinline__ float bf2f(unsigned short b) {
  union { unsigned u; float f; } v; v.u = ((unsigned)b) << 16;
  return v.f;
}
__device__ __forceinline__ float bflo(unsigned v) {
  union { unsigned u; float f; } x; x.u = v << 16; return x.f;
}
__device__ __forceinline__ float bfhi(unsigned v) {
  union { unsigned u; float f; } x; x.u = v & 0xffff0000u; return x.f;
}
// acc[0..15] += ws * (int8x16 from qv)
__device__ __forceinline__ void qfma16(float* acc, uint4 qv, float ws) {
  unsigned wd[4] = {qv.x, qv.y, qv.z, qv.w};
#pragma unroll
  for (int d = 0; d < 4; d++) {
#pragma unroll
    for (int k = 0; k < 4; k++) {
      int q = (int)((signed char)(wd[d] >> (8 * k)));
      acc[d * 4 + k] += ws * (float)q;
    }
  }
}

// Full-degree gather: one wave owns one (node, matrix) unit.
// lane -> (bb = lane>>3, 16 feats at (lane&7)*16). acc[16] out.
// Lane-parallel metadata (R9): lane l loads csr_src/csr_w[e0+l] and sc[idx] in
// ONE round; per-edge broadcast via __shfl; Gq row loads all independent.
__device__ __forceinline__ void gather_accum(const signed char* __restrict__ Gq,
                                             const float* __restrict__ sc,
                                             int e0, int e1,
                                             const int* __restrict__ csr_src,
                                             const float* __restrict__ csr_w,
                                             const float* __restrict__ dis,
                                             int n, int bb, int fo, float* acc) {
  int lane = (bb << 3) | (fo >> 4);
  int deg = e1 - e0;
  int myi = 0; float myw = 0.f;
  if (lane < deg) {
    myi = csr_src[e0 + lane];
    myw = csr_w[e0 + lane];
  }
  float mys = sc[myi];                 // lane-parallel scale gather (idx 0 if idle)
  float sn = dis[n]; sn *= sn;
  size_t rowSelf = (size_t)(n << 3) + bb;
#pragma unroll
  for (int k = 0; k < 16; k++) acc[k] = 0.f;
  {
    float ws = sn * sc[n];
    uint4 qv = *(const uint4*)&Gq[rowSelf * 128 + fo];
    qfma16(acc, qv, ws);
  }
  int dmax = deg < 64 ? deg : 64;
  int e = 0;
  for (; e + 3 < dmax; e += 4) {
    int s0 = __shfl(myi, e),     s1 = __shfl(myi, e + 1);
    int s2 = __shfl(myi, e + 2), s3 = __shfl(myi, e + 3);
    uint4 qa = *(const uint4*)&Gq[(((size_t)s0 << 3) + bb) * 128 + fo];
    uint4 qb = *(const uint4*)&Gq[(((size_t)s1 << 3) + bb) * 128 + fo];
    uint4 qc = *(const uint4*)&Gq[(((size_t)s2 << 3) + bb) * 128 + fo];
    uint4 qd = *(const uint4*)&Gq[(((size_t)s3 << 3) + bb) * 128 + fo];
    float w0 = __shfl(myw, e)     * __shfl(mys, e);
    float w1 = __shfl(myw, e + 1) * __shfl(mys, e + 1);
    float w2 = __shfl(myw, e + 2) * __shfl(mys, e + 2);
    float w3 = __shfl(myw, e + 3) * __shfl(mys, e + 3);
    qfma16(acc, qa, w0);
    qfma16(acc, qb, w1);
    qfma16(acc, qc, w2);
    qfma16(acc, qd, w3);
  }
  for (; e < dmax; e++) {
    int s0 = __shfl(myi, e);
    float w0 = __shfl(myw, e) * __shfl(mys, e);
    uint4 qa = *(const uint4*)&Gq[(((size_t)s0 << 3) + bb) * 128 + fo];
    qfma16(acc, qa, w0);
  }
  // rare tail: deg > 64 (scalar path, keeps correctness for any graph)
  for (int ee = e0 + 64; ee < e1; ee++) {
    int s0 = csr_src[ee];
    float w0 = csr_w[ee] * sc[s0];
    uint4 qa = *(const uint4*)&Gq[(((size_t)s0 << 3) + bb) * 128 + fo];
    qfma16(acc, qa, w0);
  }
}

// GRU combine, 8-element chunks, u from global bf16:
// h_new = u*h + (1-u)*tanh(acc+b); writes h back to global; o0/o1 packed rows.
__device__ __forceinline__ void gru_combine_store(const float* acc, const float* bp,
                                                  const unsigned short* __restrict__ u_in,
                                                  unsigned short* __restrict__ h_io,
                                                  size_t rowSelf, int fo,
                                                  uint4& o0, uint4& o1) {
  uint4 oo[2];
#pragma unroll
  for (int jj = 0; jj < 2; jj++) {
    uint4 uq = *(const uint4*)&u_in[rowSelf * 128 + fo + 8 * jj];
    uint4 hq = *(const uint4*)&h_io[rowSelf * 128 + fo + 8 * jj];
    float uv[8], hv[8];
    uv[0] = bflo(uq.x); uv[1] = bfhi(uq.x); uv[2] = bflo(uq.y); uv[3] = bfhi(uq.y);
    uv[4] = bflo(uq.z); uv[5] = bfhi(uq.z); uv[6] = bflo(uq.w); uv[7] = bfhi(uq.w);
    hv[0] = bflo(hq.x); hv[1] = bfhi(hq.x); hv[2] = bflo(hq.y); hv[3] = bfhi(hq.y);
    hv[4] = bflo(hq.z); hv[5] = bfhi(hq.z); hv[6] = bflo(hq.w); hv[7] = bfhi(hq.w);
    unsigned ow[4];
#pragma unroll
    for (int d = 0; d < 4; d++) {
      float v0 = acc[8 * jj + 2 * d]     + bp[8 * jj + 2 * d];
      float v1 = acc[8 * jj + 2 * d + 1] + bp[8 * jj + 2 * d + 1];
      float c0 = 1.0f - 2.0f / (__expf(2.0f * v0) + 1.0f);  // tanh
      float c1 = 1.0f - 2.0f / (__expf(2.0f * v1) + 1.0f);
      float n0 = uv[2 * d] * hv[2 * d] + (1.0f - uv[2 * d]) * c0;
      float n1 = uv[2 * d + 1] * hv[2 * d + 1] + (1.0f - uv[2 * d + 1]) * c1;
      ow[d] = (unsigned)f2bf(n0) | ((unsigned)f2bf(n1) << 16);
    }
    oo[jj].x = ow[0]; oo[jj].y = ow[1]; oo[jj].z = ow[2]; oo[jj].w = ow[3];
    *(uint4*)&h_io[rowSelf * 128 + fo + 8 * jj] = oo[jj];
  }
  o0 = oo[0]; o1 = oo[1];
}

// ---------------- graph preprocessing (once per launch) ----------------

__global__ void deg_cnt_kernel(const int* __restrict__ ei, const float* __restrict__ ew,
                               float* __restrict__ deg, int* __restrict__ cnt) {
  int e = blockIdx.x * 256 + threadIdx.x;
  if (e < EE) {
    int col = ei[EE + e];
    atomicAdd(&deg[col], ew[e]);
    atomicAdd(&cnt[col], 1);
  }
}

__global__ void dis_kernel(const float* __restrict__ deg, float* __restrict__ dis) {
  int n = blockIdx.x * 256 + threadIdx.x;
  if (n < NN) dis[n] = rsqrtf(deg[n] + 1.0f);  // +1: self-loop weight
}

__global__ void scan_kernel(const int* __restrict__ cnt, int* __restrict__ offs) {
  __shared__ int part[256];
  const int CH = (NN + 255) / 256; // 20
  int tid = threadIdx.x;
  int base = tid * CH;
  int s = 0;
  for (int i = 0; i < CH; i++) { int idx = base + i; if (idx < NN) s += cnt[idx]; }
  part[tid] = s;
  __syncthreads();
  for (int off = 1; off < 256; off <<= 1) {
    int v = (tid >= off) ? part[tid - off] : 0;
    __syncthreads();
    part[tid] += v;
    __syncthreads();
  }
  int run = (tid == 0) ? 0 : part[tid - 1];
  for (int i = 0; i < CH; i++) {
    int idx = base + i;
    if (idx < NN) { offs[idx] = run; run += cnt[idx]; }
  }
  if (tid == 255) offs[NN] = run;
}

__global__ void fill_csr_kernel(const int* __restrict__ ei, const float* __restrict__ ew,
                                const float* __restrict__ dis, const int* __restrict__ offs,
                                int* __restrict__ cursor, int* __restrict__ csr_src,
                                float* __restrict__ csr_w) {
  int e = blockIdx.x * 256 + threadIdx.x;
  if (e < EE) {
    int row = ei[e], col = ei[EE + e];
    int pos = offs[col] + atomicAdd(&cursor[col], 1);
    csr_src[pos] = row;
    csr_w[pos] = dis[row] * ew[e] * dis[col];
  }
}

// ---------------- weight prepack: fp32 [k][n] -> bf16 MFMA b-frag order ----------------

__global__ void prepack_kernel(const float* __restrict__ convW, unsigned short* __restrict__ Wp) {
  int idx = blockIdx.x * 256 + threadIdx.x;  // 6*8*8*64 = 24576
  int lane = idx & 63;
  int ks = (idx >> 6) & 7;
  int nt = (idx >> 9) & 7;
  int g = idx >> 12;
  const float* W = convW + (size_t)g * 256 * 128;
  int n = nt * 16 + (lane & 15);
  int k0 = ks * 32 + (lane >> 4) * 8;
  unsigned short v[8];
#pragma unroll
  for (int j = 0; j < 8; j++) v[j] = f2bf(W[(size_t)(k0 + j) * 128 + n]);
  *(uint4*)(Wp + (size_t)idx * 8) = *(const uint4*)v;
}

// ---------------- lin_in (bootstrap t=0 only) ----------------

__global__ __launch_bounds__(256) void lin_in_kernel(const float* __restrict__ x_seq,
                                                     const float* __restrict__ W,
                                                     const float* __restrict__ b,
                                                     unsigned short* __restrict__ xt, int t) {
  int idx = blockIdx.x * 256 + threadIdx.x;   // over TOTAL*16
  int row = idx >> 4, fh = idx & 15;          // feats 8fh..8fh+7
  int n = row >> 3, bb = row & 7;
  const float* xp = x_seq + (((size_t)bb * SS + t) * NN + n) * FF;
  float4 a0 = *(const float4*)&b[fh * 8];
  float4 a1 = *(const float4*)&b[fh * 8 + 4];
#pragma unroll
  for (int ff = 0; ff < FF; ff++) {
    float xv = xp[ff];
    float4 w0 = *(const float4*)&W[ff * HH + fh * 8];
    float4 w1 = *(const float4*)&W[ff * HH + fh * 8 + 4];
    a0.x += xv * w0.x; a0.y += xv * w0.y; a0.z += xv * w0.z; a0.w += xv * w0.w;
    a1.x += xv * w1.x; a1.y += xv * w1.y; a1.z += xv * w1.z; a1.w += xv * w1.w;
  }
  uint4 o;
  o.x = (unsigned)f2bf(fmaxf(a0.x, 0.f)) | ((unsigned)f2bf(fmaxf(a0.y, 0.f)) << 16);
  o.y = (unsigned)f2bf(fmaxf(a0.z, 0.f)) | ((unsigned)f2bf(fmaxf(a0.w, 0.f)) << 16);
  o.z = (unsigned)f2bf(fmaxf(a1.x, 0.f)) | ((unsigned)f2bf(fmaxf(a1.y, 0.f)) << 16);
  o.w = (unsigned)f2bf(fmaxf(a1.z, 0.f)) | ((unsigned)f2bf(fmaxf(a1.w, 0.f)) << 16);
  *(uint4*)&xt[(size_t)row * 128 + fh * 8] = o;
}

// ---------------- shared GEMM body (32-row tile, 8 waves) ----------------
// As (32 x 256 bf16, stride 264) staged by caller (caller syncs). MFMA, then
// per-(node,half) absmax FROM ACCUMULATORS (shfl + gmax LDS reduce), then
// int8 quantize acc directly -> byte stores to global. gmax = float[32].

template <int MT, int NTW, int HALVES, int NTHREADS>
__device__ __forceinline__ void gemm_body(const unsigned short* As, float* gmax,
                                          const unsigned short* __restrict__ Wp,
                                          signed char* __restrict__ qA,
                                          signed char* __restrict__ qB,
                                          float* __restrict__ sA,
                                          float* __restrict__ sB,
                                          int rowBase, int tid) {
  constexpr int NWAVES = NTHREADS / 64;     // 8
  constexpr int WPG = NWAVES / HALVES;      // waves per half: 4 or 8
  static_assert(MT == 2, "node mapping assumes 32-row tile");
  int wv = tid >> 6, lane = tid & 63;
  int m = lane & 15, q = lane >> 4;
  f32x4 acc[MT][NTW];
#pragma unroll
  for (int i = 0; i < MT; i++)
#pragma unroll
    for (int j = 0; j < NTW; j++) acc[i][j] = (f32x4)(0.0f);
  const unsigned short* wbase = Wp + ((size_t)(wv * NTW) * 8 * 64 + lane) * 8;
#pragma unroll
  for (int ks = 0; ks < 8; ks++) {
    short8 a[MT];
#pragma unroll
    for (int mt = 0; mt < MT; mt++)
      a[mt] = *(const short8*)&As[(mt * 16 + m) * 264 + ks * 32 + q * 8];
#pragma unroll
    for (int nt = 0; nt < NTW; nt++) {
      short8 b = *(const short8*)(wbase + (size_t)(nt * 8 + ks) * 64 * 8);
#pragma unroll
      for (int mt = 0; mt < MT; mt++)
        acc[mt][nt] = __builtin_amdgcn_mfma_f32_16x16x32_bf16(a[mt], b, acc[mt][nt], 0, 0, 0);
    }
  }
  // Per-lane row->node mapping: rows mt*16+q*4+i; node = mt*2 + (q>>1).
  float mxa = 0.f, mxb = 0.f;
#pragma unroll
  for (int nt = 0; nt < NTW; nt++)
#pragma unroll
    for (int i = 0; i < 4; i++) {
      mxa = fmaxf(mxa, fabsf(acc[0][nt][i]));
      mxb = fmaxf(mxb, fabsf(acc[1][nt][i]));
    }
#pragma unroll
  for (int off = 16; off; off >>= 1) {
    mxa = fmaxf(mxa, __shfl_down(mxa, off));
    mxb = fmaxf(mxb, __shfl_down(mxb, off));
  }
  if (lane == 0)  { gmax[wv * 4 + 0] = mxa; gmax[wv * 4 + 2] = mxb; }
  if (lane == 32) { gmax[wv * 4 + 1] = mxa; gmax[wv * 4 + 3] = mxb; }
  __syncthreads();
  // global per-(node,half) scale
  if (tid < 4 * HALVES) {
    int node = (HALVES == 2) ? (tid >> 1) : tid;
    int half = (HALVES == 2) ? (tid & 1) : 0;
    float g = 0.f;
#pragma unroll
    for (int w = 0; w < WPG; w++) g = fmaxf(g, gmax[(half * WPG + w) * 4 + node]);
    float* sp = half ? sB : sA;
    sp[(rowBase >> 3) + node] = g * (1.0f / 127.0f);
  }
  // per-lane inverse scales for its two nodes
  int half = (HALVES == 2) ? (wv / WPG) : 0;
  int qh = q >> 1;
  float ga = 0.f, gb = 0.f;
#pragma unroll
  for (int w = 0; w < WPG; w++) {
    ga = fmaxf(ga, gmax[(half * WPG + w) * 4 + qh]);
    gb = fmaxf(gb, gmax[(half * WPG + w) * 4 + 2 + qh]);
  }
  float invA = (ga > 0.f) ? (127.0f / ga) : 0.f;
  float invB = (gb > 0.f) ? (127.0f / gb) : 0.f;
  // quantize acc directly -> byte stores (rows strided by 128B)
  signed char* qbase = (half ? qB : qA);
#pragma unroll
  for (int mt = 0; mt < MT; mt++) {
    float inv = mt ? invB : invA;
#pragma unroll
    for (int nt = 0; nt < NTW; nt++) {
      int colq = (wv * NTW + nt) * 16 + m - half * 128;
      signed char* dst = qbase + (size_t)(rowBase + mt * 16 + q * 4) * 128 + colq;
#pragma unroll
      for (int i = 0; i < 4; i++) {
        int qv = __float2int_rn(acc[mt][nt][i] * inv);
        dst[(size_t)i * 128] = (signed char)qv;
      }
    }
  }
}

// ---------------- cooperative-loop parameter block ----------------

struct CoopParams {
  const signed char* GqR; const signed char* GqU; signed char* Cq;
  float* sR; float* sU; float* sC;
  const int* offs; const int* csr_src; const float* csr_w; const float* dis;
  const float* convB;
  unsigned short* h0; unsigned short* h1; unsigned short* xt; unsigned short* ub;
  const float* x_seq; const float* Win; const float* bin;
  const unsigned short* Wg0; const unsigned short* Wc0;
  const unsigned short* Wg1; const unsigned short* Wc1;
};

// ---- phase bodies (identical math to R9's kernels, rowBase = tile*32) ----

__device__ __forceinline__ void phase_cand(unsigned short* As, float* gmax,
    const CoopParams& p, int rowBase,
    const signed char* GqRg, const signed char* GqUg,
    const float* sRg, const float* sUg,
    const float* bRU, const unsigned short* h, unsigned short* u_out,
    const unsigned short* A1, const unsigned short* Wp) {
  int tid = threadIdx.x;
  int wv = tid >> 6, lane = tid & 63;
  int gn0 = rowBase >> 3;
  int bb = lane >> 3, fo = (lane & 7) << 4;
  int node8 = wv >> 1, half = wv & 1;
  int n = gn0 + node8;
  int e0 = p.offs[n], e1 = p.offs[n + 1];
  {
    int row = tid >> 4, sub = tid & 15;
    *(uint4*)&As[row * 264 + sub * 8] =
        *(const uint4*)&A1[(size_t)(rowBase + row) * 128 + sub * 8];
  }
  float acc[16];
  gather_accum(half ? GqUg : GqRg, half ? sUg : sRg, e0, e1, p.csr_src, p.csr_w,
               p.dis, n, bb, fo, acc);
  const float* bias = bRU + half * 128 + fo;
  size_t rowSelf = ((size_t)n << 3) + bb;
  if (half == 0) {
    int lr = node8 * 8 + bb;
#pragma unroll
    for (int jj = 0; jj < 2; jj++) {
      uint4 hq = *(const uint4*)&h[rowSelf * 128 + fo + 8 * jj];
      float hv[8];
      hv[0] = bflo(hq.x); hv[1] = bfhi(hq.x); hv[2] = bflo(hq.y); hv[3] = bfhi(hq.y);
      hv[4] = bflo(hq.z); hv[5] = bfhi(hq.z); hv[6] = bflo(hq.w); hv[7] = bfhi(hq.w);
      unsigned ow[4];
#pragma unroll
      for (int d = 0; d < 4; d++) {
        float s0 = 1.0f / (1.0f + __expf(-(acc[8 * jj + 2 * d]     + bias[8 * jj + 2 * d])));
        float s1 = 1.0f / (1.0f + __expf(-(acc[8 * jj + 2 * d + 1] + bias[8 * jj + 2 * d + 1])));
        ow[d] = (unsigned)f2bf(s0 * hv[2 * d]) | ((unsigned)f2bf(s1 * hv[2 * d + 1]) << 16);
      }
      uint4 o; o.x = ow[0]; o.y = ow[1]; o.z = ow[2]; o.w = ow[3];
      *(uint4*)&As[lr * 264 + 128 + fo + 8 * jj] = o;
    }
  } else {
#pragma unroll
    for (int jj = 0; jj < 2; jj++) {
      unsigned ow[4];
#pragma unroll
      for (int d = 0; d < 4; d++) {
        float s0 = 1.0f / (1.0f + __expf(-(acc[8 * jj + 2 * d]     + bias[8 * jj + 2 * d])));
        float s1 = 1.0f / (1.0f + __expf(-(acc[8 * jj + 2 * d + 1] + bias[8 * jj + 2 * d + 1])));
        ow[d] = (unsigned)f2bf(s0) | ((unsigned)f2bf(s1) << 16);
      }
      uint4 o; o.x = ow[0]; o.y = ow[1]; o.z = ow[2]; o.w = ow[3];
      *(uint4*)&u_out[rowSelf * 128 + fo + 8 * jj] = o;
    }
  }
  __syncthreads();
  gemm_body<2, 1, 1, 512>(As, gmax, Wp, p.Cq, p.Cq, p.sC, p.sC, rowBase, tid);
}

__device__ __forceinline__ void phase_gates(unsigned short* As, float* gmax,
    const CoopParams& p, int rowBase,
    const float* bC, const unsigned short* u_in, unsigned short* h_io,
    const unsigned short* A2src, const unsigned short* Wp,
    signed char* GqRo, signed char* GqUo, float* sRo, float* sUo) {
  int tid = threadIdx.x;
  int wv = tid >> 6, lane = tid & 63;
  int gn0 = rowBase >> 3;
  int bb = lane >> 3, fo = (lane & 7) << 4;
  if (wv >= 4) {
    int t2 = tid - 256;
    for (int c = t2; c < 512; c += 256) {
      int row = c >> 4, sub = c & 15;
      *(uint4*)&As[row * 264 + 128 + sub * 8] =
          *(const uint4*)&A2src[(size_t)(rowBase + row) * 128 + sub * 8];
    }
  } else {
    int node8 = wv;
    int n = gn0 + node8;
    int e0 = p.offs[n], e1 = p.offs[n + 1];
    float acc[16];
    gather_accum(p.Cq, p.sC, e0, e1, p.csr_src, p.csr_w, p.dis, n, bb, fo, acc);
    size_t rowSelf = ((size_t)n << 3) + bb;
    uint4 o0, o1;
    gru_combine_store(acc, bC + fo, u_in, h_io, rowSelf, fo, o0, o1);
    int lr = node8 * 8 + bb;
    *(uint4*)&As[lr * 264 + fo] = o0;
    *(uint4*)&As[lr * 264 + fo + 8] = o1;
  }
  __syncthreads();
  gemm_body<2, 2, 2, 512>(As, gmax, Wp, GqRo, GqUo, sRo, sUo, rowBase, tid);
}

__device__ __forceinline__ void phase_gates_lin(unsigned short* As, float* gmax,
    const CoopParams& p, int rowBase,
    const float* bC, const unsigned short* u_in, unsigned short* h_io,
    const unsigned short* A2src, const unsigned short* Wp,
    signed char* GqRo, signed char* GqUo, float* sRo, float* sUo, int t_next) {
  int tid = threadIdx.x;
  int wv = tid >> 6, lane = tid & 63;
  int gn0 = rowBase >> 3;
  int bb = lane >> 3, fo = (lane & 7) << 4;
  if (wv < 4) {
    int node8 = wv;
    int n = gn0 + node8;
    int e0 = p.offs[n], e1 = p.offs[n + 1];
    float acc[16];
    gather_accum(p.Cq, p.sC, e0, e1, p.csr_src, p.csr_w, p.dis, n, bb, fo, acc);
    size_t rowSelf = ((size_t)n << 3) + bb;
    uint4 o0, o1;
    gru_combine_store(acc, bC + fo, u_in, h_io, rowSelf, fo, o0, o1);
  } else {
    int t2 = tid - 256;
    for (int c = t2; c < 512; c += 256) {
      int row = c >> 4, sub = c & 15;
      *(uint4*)&As[row * 264 + 128 + sub * 8] =
          *(const uint4*)&A2src[(size_t)(rowBase + row) * 128 + sub * 8];
    }
    for (int c = t2; c < 512; c += 256) {
      int row = c >> 4, fh = c & 15;
      int grow = rowBase + row;
      int n2 = grow >> 3, bbv = grow & 7;
      const float* xp = p.x_seq + (((size_t)bbv * SS + t_next) * NN + n2) * FF;
      float4 a0 = *(const float4*)&p.bin[fh * 8];
      float4 a1 = *(const float4*)&p.bin[fh * 8 + 4];
#pragma unroll
      for (int ff = 0; ff < FF; ff++) {
        float xv = xp[ff];
        float4 w0 = *(const float4*)&p.Win[ff * HH + fh * 8];
        float4 w1 = *(const float4*)&p.Win[ff * HH + fh * 8 + 4];
        a0.x += xv * w0.x; a0.y += xv * w0.y; a0.z += xv * w0.z; a0.w += xv * w0.w;
        a1.x += xv * w1.x; a1.y += xv * w1.y; a1.z += xv * w1.z; a1.w += xv * w1.w;
      }
      uint4 o;
      o.x = (unsigned)f2bf(fmaxf(a0.x, 0.f)) | ((unsigned)f2bf(fmaxf(a0.y, 0.f)) << 16);
      o.y = (unsigned)f2bf(fmaxf(a0.z, 0.f)) | ((unsigned)f2bf(fmaxf(a0.w, 0.f)) << 16);
      o.z = (unsigned)f2bf(fmaxf(a1.x, 0.f)) | ((unsigned)f2bf(fmaxf(a1.y, 0.f)) << 16);
      o.w = (unsigned)f2bf(fmaxf(a1.z, 0.f)) | ((unsigned)f2bf(fmaxf(a1.w, 0.f)) << 16);
      *(uint4*)&As[row * 264 + fh * 8] = o;
      *(uint4*)&p.xt[(size_t)grow * 128 + fh * 8] = o;
    }
  }
  __syncthreads();
  gemm_body<2, 2, 2, 512>(As, gmax, Wp, GqRo, GqUo, sRo, sUo, rowBase, tid);
}

__device__ __forceinline__ void phase_final(const CoopParams& p, int rowBase,
    const float* bC, const unsigned short* u_in, unsigned short* h_io) {
  int tid = threadIdx.x;
  int wv = tid >> 6, lane = tid & 63;
  if (wv >= 4) return;
  int gn0 = rowBase >> 3;
  int bb = lane >> 3, fo = (lane & 7) << 4;
  int n = gn0 + wv;
  int e0 = p.offs[n], e1 = p.offs[n + 1];
  float acc[16];
  gather_accum(p.Cq, p.sC, e0, e1, p.csr_src, p.csr_w, p.dis, n, bb, fo, acc);
  size_t rowSelf = ((size_t)n << 3) + bb;
  uint4 o0, o1;
  gru_combine_store(acc, bC + fo, u_in, h_io, rowSelf, fo, o0, o1);
}

// ---------------- THE persistent cooperative loop kernel ----------------

__global__ __launch_bounds__(512, 8) void tgcn_loop_kernel(CoopParams p) {
  __shared__ unsigned short As[32 * 264];
  __shared__ float gmax[32];
  cg::grid_group gg = cg::this_grid();
  const float* bRU0 = p.convB;
  const float* bC0  = p.convB + 2 * HH;
  const float* bRU1 = p.convB + 3 * HH;
  const float* bC1  = p.convB + 5 * HH;
  for (int t = 0; t < SS; t++) {
    // B: gates0-gather -> rh0(LDS), u0 -> cand0 GEMM -> Cq
    for (int tile = blockIdx.x; tile < NTILES; tile += gridDim.x)
      phase_cand(As, gmax, p, tile * 32, p.GqR, p.GqU, p.sR, p.sU, bRU0, p.h0, p.ub,
                 p.xt, p.Wc0);
    gg.sync();
    // C: cand0-gather -> h0 update -> gates1 GEMM -> GqR/GqU
    for (int tile = blockIdx.x; tile < NTILES; tile += gridDim.x)
      phase_gates(As, gmax, p, tile * 32, bC0, p.ub, p.h0, p.h1, p.Wg1,
                  (signed char*)p.GqR, (signed char*)p.GqU, p.sR, p.sU);
    gg.sync();
    // D: gates1-gather -> rh1(LDS), u1 -> cand1 GEMM -> Cq
    for (int tile = blockIdx.x; tile < NTILES; tile += gridDim.x)
      phase_cand(As, gmax, p, tile * 32, p.GqR, p.GqU, p.sR, p.sU, bRU1, p.h1, p.ub,
                 p.h0, p.Wc1);
    gg.sync();
    // E: cand1-gather -> h1 update (+ lin_in(t+1) + gates0 GEMM if t<SS-1)
    if (t < SS - 1) {
      for (int tile = blockIdx.x; tile < NTILES; tile += gridDim.x)
        phase_gates_lin(As, gmax, p, tile * 32, bC1, p.ub, p.h1, p.h0, p.Wg0,
                        (signed char*)p.GqR, (signed char*)p.GqU, p.sR, p.sU, t + 1);
      gg.sync();
    } else {
      for (int tile = blockIdx.x; tile < NTILES; tile += gridDim.x)
        phase_final(p, tile * 32, bC1, p.ub, p.h1);
    }
  }
}

// ---------------- bootstrap GEMM (stages both halves from global) ----------------

template <int NTW, int HALVES>
__global__ __launch_bounds__(512) void gemm_mfma_q(const unsigned short* __restrict__ A1,
                                                   const unsigned short* __restrict__ A2,
                                                   const unsigned short* __restrict__ Wp,
                                                   signed char* __restrict__ qA,
                                                   signed char* __restrict__ qB,
                                                   float* __restrict__ sA,
                                                   float* __restrict__ sB) {
  __shared__ unsigned short As[32 * 264];
  __shared__ float gmax[32];
  int rowBase = blockIdx.x * 32;
  int tid = threadIdx.x;
  for (int c = tid; c < 1024; c += 512) {
    int row = c >> 5; int rest = c & 31; int half = rest >> 4; int sub = rest & 15;
    const unsigned short* src = (half ? A2 : A1) + ((size_t)(rowBase + row) * 128 + sub * 8);
    *(uint4*)&As[row * 264 + half * 128 + sub * 8] = *(const uint4*)src;
  }
  __syncthreads();
  gemm_body<2, NTW, HALVES, 512>(As, gmax, Wp, qA, qB, sA, sB, rowBase, tid);
}

// ---------------- fallback multi-kernel phases (R9, used if coop launch fails) ----

__global__ __launch_bounds__(512, 8) void fused_cand_q(
    CoopParams p, const float* bRU, const unsigned short* h,
    const unsigned short* A1, const unsigned short* Wp) {
  __shared__ unsigned short As[32 * 264];
  __shared__ float gmax[32];
  phase_cand(As, gmax, p, blockIdx.x * 32, p.GqR, p.GqU, p.sR, p.sU, bRU, h, p.ub, A1, Wp);
}

__global__ __launch_bounds__(512, 8) void fused_gates_q(
    CoopParams p, const float* bC, unsigned short* h_io,
    const unsigned short* A2src, const unsigned short* Wp) {
  __shared__ unsigned short As[32 * 264];
  __shared__ float gmax[32];
  phase_gates(As, gmax, p, blockIdx.x * 32, bC, p.ub, h_io, A2src, Wp,
              (signed char*)p.GqR, (signed char*)p.GqU, p.sR, p.sU);
}

__global__ __launch_bounds__(512, 8) void fused_gates_lin_q(
    CoopParams p, const float* bC, unsigned short* h_io,
    const unsigned short* A2src, const unsigned short* Wp, int t_next) {
  __shared__ unsigned short As[32 * 264];
  __shared__ float gmax[32];
  phase_gates_lin(As, gmax, p, blockIdx.x * 32, bC, p.ub, h_io, A2src, Wp,
                  (signed char*)p.GqR, (signed char*)p.GqU, p.sR, p.sU, t_next);
}

__global__ __launch_bounds__(512) void scatter_c_update_q(
    CoopParams p, const float* bC, unsigned short* h_io) {
  phase_final(p, blockIdx.x * 32, bC, p.ub, h_io);
}

// ---------------- BatchNorm stats ----------------

__global__ __launch_bounds__(256) void bn_stats_kernel(const unsigned short* __restrict__ h,
                                                       float* __restrict__ sums) {
  __shared__ float ls[512];
  int tid = threadIdx.x;
  float s = 0.f, sq = 0.f;
  for (size_t idx = (size_t)blockIdx.x * 256 + tid; idx < (size_t)TOTAL * HH;
       idx += (size_t)gridDim.x * 256) {
    float v = bf2f(h[idx]);
    s += v; sq += v * v;
  }
  ls[tid] = s; ls[256 + tid] = sq;
  __syncthreads();
  if (tid < 128) {
    atomicAdd(&sums[tid], ls[tid] + ls[tid + 128]);
    atomicAdd(&sums[128 + tid], ls[256 + tid] + ls[256 + tid + 128]);
  }
}

// ---------------- fused BN -> relu -> lin_out -> log_softmax ----------------

__global__ __launch_bounds__(256) void final_kernel(const unsigned short* __restrict__ h,
                                                    const float* __restrict__ sums,
                                                    const float* __restrict__ gamma,
                                                    const float* __restrict__ beta,
                                                    const float* __restrict__ Wout,
                                                    const float* __restrict__ bout,
                                                    float* __restrict__ out) {
  int wid = threadIdx.x >> 6, lane = threadIdx.x & 63;
  int row = blockIdx.x * 4 + wid; // node-row (n*8+bb order)
  if (row >= TOTAL) return;
  const float inv = 1.0f / (float)TOTAL;
  float p0 = 0.f, p1 = 0.f, p2 = 0.f, p3 = 0.f;
#pragma unroll
  for (int jj = 0; jj < 2; jj++) {
    int j = lane + jj * 64;
    float mean = sums[j] * inv;
    float var = sums[128 + j] * inv - mean * mean;
    float hn = (bf2f(h[(size_t)row * HH + j]) - mean) * rsqrtf(var + 1e-5f) * gamma[j] + beta[j];
    hn = fmaxf(hn, 0.0f);
    p0 += hn * Wout[j * 4 + 0];
    p1 += hn * Wout[j * 4 + 1];
    p2 += hn * Wout[j * 4 + 2];
    p3 += hn * Wout[j * 4 + 3];
  }
  for (int off = 32; off; off >>= 1) {
    p0 += __shfl_down(p0, off);
    p1 += __shfl_down(p1, off);
    p2 += __shfl_down(p2, off);
    p3 += __shfl_down(p3, off);
  }
  if (lane == 0) {
    p0 += bout[0]; p1 += bout[1]; p2 += bout[2]; p3 += bout[3];
    float m = fmaxf(fmaxf(p0, p1), fmaxf(p2, p3));
    float e = __expf(p0 - m) + __expf(p1 - m) + __expf(p2 - m) + __expf(p3 - m);
    float lse = m + __logf(e);
    int bb = row & 7, n = row >> 3;
    float* o = out + ((size_t)bb * NN + n) * 4;
    o[0] = p0 - lse; o[1] = p1 - lse; o[2] = p2 - lse; o[3] = p3 - lse;
  }
}

// ---------------- launcher ----------------

extern "C" void kernel_launch(void* const* d_in, const int* in_sizes, int n_in,
                              void* d_out, int out_size, void* d_ws, size_t ws_size,
                              hipStream_t stream) {
  const float* x_seq = (const float*)d_in[0];
  const int* ei      = (const int*)d_in[1];
  const float* ew    = (const float*)d_in[2];
  const float* Win   = (const float*)d_in[3];
  const float* bin   = (const float*)d_in[4];
  const float* convW = (const float*)d_in[5];
  const float* convB = (const float*)d_in[6];
  const float* gamma = (const float*)d_in[7];
  const float* beta  = (const float*)d_in[8];
  const float* Wout  = (const float*)d_in[9];
  const float* bout  = (const float*)d_in[10];
  float* out = (float*)d_out;

  char* ws = (char*)d_ws;
  size_t off = 0;
  auto alloc = [&](size_t bytes) {
    void* p = ws + off;
    off += (bytes + 1023) & ~(size_t)1023;
    return p;
  };
  float* deg     = (float*)alloc(NN * 4);
  float* dis     = (float*)alloc(NN * 4);
  int*   cnt     = (int*)alloc(NN * 4);
  int*   offs    = (int*)alloc((NN + 1) * 4);
  int*   cursor  = (int*)alloc(NN * 4);
  int*   csr_src = (int*)alloc(EE * 4);
  float* csr_w   = (float*)alloc(EE * 4);
  float* sums    = (float*)alloc(256 * 4);
  float* sR      = (float*)alloc(NN * 4);
  float* sU      = (float*)alloc(NN * 4);
  float* sC      = (float*)alloc(NN * 4);
  unsigned short* Wp = (unsigned short*)alloc(6 * 32768 * 2);  // packed conv weights
  const size_t NH = (size_t)TOTAL * HH; // 5,120,000
  unsigned short* h0 = (unsigned short*)alloc(NH * 2);
  unsigned short* h1 = (unsigned short*)alloc(NH * 2);
  unsigned short* xt = (unsigned short*)alloc(NH * 2);
  unsigned short* ub = (unsigned short*)alloc(NH * 2);
  signed char* GqR = (signed char*)alloc(NH);   // int8 messages
  signed char* GqU = (signed char*)alloc(NH);
  signed char* Cq  = (signed char*)alloc(NH);   // DEDICATED (no alias with GqR!)

  hipMemsetAsync(deg, 0, NN * 4, stream);
  hipMemsetAsync(cnt, 0, NN * 4, stream);
  hipMemsetAsync(cursor, 0, NN * 4, stream);
  hipMemsetAsync(sums, 0, 256 * 4, stream);
  hipMemsetAsync(h0, 0, NH * 2, stream);
  hipMemsetAsync(h1, 0, NH * 2, stream);

  deg_cnt_kernel<<<(EE + 255) / 256, 256, 0, stream>>>(ei, ew, deg, cnt);
  dis_kernel<<<(NN + 255) / 256, 256, 0, stream>>>(deg, dis);
  scan_kernel<<<1, 256, 0, stream>>>(cnt, offs);
  fill_csr_kernel<<<(EE + 255) / 256, 256, 0, stream>>>(ei, ew, dis, offs, cursor, csr_src, csr_w);
  prepack_kernel<<<24576 / 256, 256, 0, stream>>>(convW, Wp);

  CoopParams cp;
  cp.GqR = GqR; cp.GqU = GqU; cp.Cq = Cq;
  cp.sR = sR; cp.sU = sU; cp.sC = sC;
  cp.offs = offs; cp.csr_src = csr_src; cp.csr_w = csr_w; cp.dis = dis;
  cp.convB = convB;
  cp.h0 = h0; cp.h1 = h1; cp.xt = xt; cp.ub = ub;
  cp.x_seq = x_seq; cp.Win = Win; cp.bin = bin;
  cp.Wg0 = Wp;
  cp.Wc0 = Wp + (size_t)2 * 32768;
  cp.Wg1 = Wp + (size_t)3 * 32768;
  cp.Wc1 = Wp + (size_t)5 * 32768;

  const float* bRU0 = convB;
  const float* bC0  = convB + 2 * HH;
  const float* bRU1 = convB + 3 * HH;
  const float* bC1  = convB + 5 * HH;

  // bootstrap: xt(t=0), gates0(t=0)
  lin_in_kernel<<<TOTAL * 16 / 256, 256, 0, stream>>>(x_seq, Win, bin, xt, 0);
  gemm_mfma_q<2, 2><<<TOTAL / 32, 512, 0, stream>>>(xt, h0, cp.Wg0, GqR, GqU, sR, sU);

  // persistent cooperative loop (grid sized to guaranteed co-residency)
  int occ = 0;
  hipOccupancyMaxActiveBlocksPerMultiprocessor(&occ, tgcn_loop_kernel, 512, 0);
  int grid = occ * 256;
  if (grid > NTILES) grid = NTILES;
  hipError_t cerr = hipErrorUnknown;
  if (grid >= 64) {
    void* kargs[] = { (void*)&cp };
    cerr = hipLaunchCooperativeKernel((void*)tgcn_loop_kernel, dim3(grid), dim3(512),
                                      kargs, 0, stream);
  }
  if (cerr != hipSuccess) {
    // fallback: R9 multi-kernel schedule (identical math)
    for (int t = 0; t < SS; t++) {
      fused_cand_q<<<NTILES, 512, 0, stream>>>(cp, bRU0, h0, xt, cp.Wc0);
      fused_gates_q<<<NTILES, 512, 0, stream>>>(cp, bC0, h0, h1, cp.Wg1);
      fused_cand_q<<<NTILES, 512, 0, stream>>>(cp, bRU1, h1, h0, cp.Wc1);
      if (t < SS - 1) {
        fused_gates_lin_q<<<NTILES, 512, 0, stream>>>(cp, bC1, h1, h0, cp.Wg0, t + 1);
      } else {
        scatter_c_update_q<<<NTILES, 512, 0, stream>>>(cp, bC1, h1);
      }
    }
  }

  bn_stats_kernel<<<256, 256, 0, stream>>>(h1, sums);
  final_kernel<<<TOTAL / 4, 256, 0, stream>>>(h1, sums, gamma, beta, Wout, bout, out);
}

// Round 11
// 1958.766 us; speedup vs baseline: 3.0022x; 3.0022x over previous
//
#include <hip/hip_runtime.h>
#include <cstdint>
#include <cstddef>

#define NN 5000     // nodes per batch block
#define EE 40000    // edges per batch block
#define BATCH 8
#define SS 12
#define FF 16
#define HH 128
#define TOTAL 40000 // BATCH*NN
#define CC 4

// Layout: per-row state arrays use row = n*8 + bb (batch-interleaved). Gather-only
// message matrices are INT8 with one fp32 scale per source node per matrix.
//
// Fused schedule (R9 champion): B cand0-GEMM, C gates1-GEMM, D cand1-GEMM,
// E gates0-GEMM(+lin_in t+1); each kernel's PROLOGUE gathers the previous
// GEMM's messages for its own 4 nodes. 32-row tiles, 512 threads, 4 blk/CU.
//
// R11 = R9 + 8-WIDE GATHER ISSUE: all Gq row loads are independent (lane-
// parallel metadata, R9); issue 8 before consuming instead of 4 -> half the
// latency exposures per gather unit (mean deg ~8 => typically ONE round).
// (R10's persistent cooperative loop REGRESSED 3.9x: grid.sync on 8 non-
// coherent XCD L2s costs far more than a kernel launch — refuted.)
//
// CORRECTNESS (G16): Cq dedicated (not aliasing GqR) — cross-block race at
// grid > co-residency, proven in R2.

typedef __attribute__((ext_vector_type(8))) short short8;   // 8 bf16 (4 VGPRs)
typedef __attribute__((ext_vector_type(4))) float f32x4;    // 4 fp32

__device__ __forceinline__ unsigned short f2bf(float f) {
  union { float f; unsigned u; } v; v.f = f;
  unsigned r = v.u + 0x7fff + ((v.u >> 16) & 1);  // RTNE
  return (unsigned short)(r >> 16);
}
__device__ __forceinline__ float bf2f(unsigned short b) {
  union { unsigned u; float f; } v; v.u = ((unsigned)b) << 16;
  return v.f;
}
__device__ __forceinline__ float bflo(unsigned v) {
  union { unsigned u; float f; } x; x.u = v << 16; return x.f;
}
__device__ __forceinline__ float bfhi(unsigned v) {
  union { unsigned u; float f; } x; x.u = v & 0xffff0000u; return x.f;
}
// acc[0..15] += ws * (int8x16 from qv)
__device__ __forceinline__ void qfma16(float* acc, uint4 qv, float ws) {
  unsigned wd[4] = {qv.x, qv.y, qv.z, qv.w};
#pragma unroll
  for (int d = 0; d < 4; d++) {
#pragma unroll
    for (int k = 0; k < 4; k++) {
      int q = (int)((signed char)(wd[d] >> (8 * k)));
      acc[d * 4 + k] += ws * (float)q;
    }
  }
}

// Full-degree gather: one wave owns one (node, matrix) unit.
// lane -> (bb = lane>>3, 16 feats at (lane&7)*16). acc[16] out.
// Lane-parallel metadata: lane l loads csr_src/csr_w[e0+l] and sc[idx] in ONE
// round; per-edge broadcast via __shfl; Gq row loads all independent, issued
// 8 at a time before any consume (R11).
__device__ __forceinline__ void gather_accum(const signed char* __restrict__ Gq,
                                             const float* __restrict__ sc,
                                             int e0, int e1,
                                             const int* __restrict__ csr_src,
                                             const float* __restrict__ csr_w,
                                             const float* __restrict__ dis,
                                             int n, int bb, int fo, float* acc) {
  int lane = (bb << 3) | (fo >> 4);
  int deg = e1 - e0;
  int myi = 0; float myw = 0.f;
  if (lane < deg) {
    myi = csr_src[e0 + lane];
    myw = csr_w[e0 + lane];
  }
  float mys = sc[myi];                 // lane-parallel scale gather (idx 0 if idle)
  float sn = dis[n]; sn *= sn;
  size_t rowSelf = (size_t)(n << 3) + bb;
#pragma unroll
  for (int k = 0; k < 16; k++) acc[k] = 0.f;
  {
    float ws = sn * sc[n];
    uint4 qv = *(const uint4*)&Gq[rowSelf * 128 + fo];
    qfma16(acc, qv, ws);
  }
  int dmax = deg < 64 ? deg : 64;
  int e = 0;
  for (; e + 7 < dmax; e += 8) {
    uint4 qv[8];
    float w[8];
#pragma unroll
    for (int j = 0; j < 8; j++) {
      int s = __shfl(myi, e + j);
      qv[j] = *(const uint4*)&Gq[(((size_t)s << 3) + bb) * 128 + fo];
      w[j] = __shfl(myw, e + j) * __shfl(mys, e + j);
    }
#pragma unroll
    for (int j = 0; j < 8; j++) qfma16(acc, qv[j], w[j]);
  }
  for (; e + 3 < dmax; e += 4) {
    uint4 qv[4];
    float w[4];
#pragma unroll
    for (int j = 0; j < 4; j++) {
      int s = __shfl(myi, e + j);
      qv[j] = *(const uint4*)&Gq[(((size_t)s << 3) + bb) * 128 + fo];
      w[j] = __shfl(myw, e + j) * __shfl(mys, e + j);
    }
#pragma unroll
    for (int j = 0; j < 4; j++) qfma16(acc, qv[j], w[j]);
  }
  for (; e < dmax; e++) {
    int s0 = __shfl(myi, e);
    float w0 = __shfl(myw, e) * __shfl(mys, e);
    uint4 qa = *(const uint4*)&Gq[(((size_t)s0 << 3) + bb) * 128 + fo];
    qfma16(acc, qa, w0);
  }
  // rare tail: deg > 64 (scalar path, keeps correctness for any graph)
  for (int ee = e0 + 64; ee < e1; ee++) {
    int s0 = csr_src[ee];
    float w0 = csr_w[ee] * sc[s0];
    uint4 qa = *(const uint4*)&Gq[(((size_t)s0 << 3) + bb) * 128 + fo];
    qfma16(acc, qa, w0);
  }
}

// GRU combine, 8-element chunks (low register pressure), u from global bf16:
// h_new = u*h + (1-u)*tanh(acc+b); writes h back to global; o0/o1 packed rows.
__device__ __forceinline__ void gru_combine_store(const float* acc, const float* bp,
                                                  const unsigned short* __restrict__ u_in,
                                                  unsigned short* __restrict__ h_io,
                                                  size_t rowSelf, int fo,
                                                  uint4& o0, uint4& o1) {
  uint4 oo[2];
#pragma unroll
  for (int jj = 0; jj < 2; jj++) {
    uint4 uq = *(const uint4*)&u_in[rowSelf * 128 + fo + 8 * jj];
    uint4 hq = *(const uint4*)&h_io[rowSelf * 128 + fo + 8 * jj];
    float uv[8], hv[8];
    uv[0] = bflo(uq.x); uv[1] = bfhi(uq.x); uv[2] = bflo(uq.y); uv[3] = bfhi(uq.y);
    uv[4] = bflo(uq.z); uv[5] = bfhi(uq.z); uv[6] = bflo(uq.w); uv[7] = bfhi(uq.w);
    hv[0] = bflo(hq.x); hv[1] = bfhi(hq.x); hv[2] = bflo(hq.y); hv[3] = bfhi(hq.y);
    hv[4] = bflo(hq.z); hv[5] = bfhi(hq.z); hv[6] = bflo(hq.w); hv[7] = bfhi(hq.w);
    unsigned ow[4];
#pragma unroll
    for (int d = 0; d < 4; d++) {
      float v0 = acc[8 * jj + 2 * d]     + bp[8 * jj + 2 * d];
      float v1 = acc[8 * jj + 2 * d + 1] + bp[8 * jj + 2 * d + 1];
      float c0 = 1.0f - 2.0f / (__expf(2.0f * v0) + 1.0f);  // tanh
      float c1 = 1.0f - 2.0f / (__expf(2.0f * v1) + 1.0f);
      float n0 = uv[2 * d] * hv[2 * d] + (1.0f - uv[2 * d]) * c0;
      float n1 = uv[2 * d + 1] * hv[2 * d + 1] + (1.0f - uv[2 * d + 1]) * c1;
      ow[d] = (unsigned)f2bf(n0) | ((unsigned)f2bf(n1) << 16);
    }
    oo[jj].x = ow[0]; oo[jj].y = ow[1]; oo[jj].z = ow[2]; oo[jj].w = ow[3];
    *(uint4*)&h_io[rowSelf * 128 + fo + 8 * jj] = oo[jj];
  }
  o0 = oo[0]; o1 = oo[1];
}

// ---------------- graph preprocessing (once per launch) ----------------

__global__ void deg_cnt_kernel(const int* __restrict__ ei, const float* __restrict__ ew,
                               float* __restrict__ deg, int* __restrict__ cnt) {
  int e = blockIdx.x * 256 + threadIdx.x;
  if (e < EE) {
    int col = ei[EE + e];
    atomicAdd(&deg[col], ew[e]);
    atomicAdd(&cnt[col], 1);
  }
}

__global__ void dis_kernel(const float* __restrict__ deg, float* __restrict__ dis) {
  int n = blockIdx.x * 256 + threadIdx.x;
  if (n < NN) dis[n] = rsqrtf(deg[n] + 1.0f);  // +1: self-loop weight
}

__global__ void scan_kernel(const int* __restrict__ cnt, int* __restrict__ offs) {
  __shared__ int part[256];
  const int CH = (NN + 255) / 256; // 20
  int tid = threadIdx.x;
  int base = tid * CH;
  int s = 0;
  for (int i = 0; i < CH; i++) { int idx = base + i; if (idx < NN) s += cnt[idx]; }
  part[tid] = s;
  __syncthreads();
  for (int off = 1; off < 256; off <<= 1) {
    int v = (tid >= off) ? part[tid - off] : 0;
    __syncthreads();
    part[tid] += v;
    __syncthreads();
  }
  int run = (tid == 0) ? 0 : part[tid - 1];
  for (int i = 0; i < CH; i++) {
    int idx = base + i;
    if (idx < NN) { offs[idx] = run; run += cnt[idx]; }
  }
  if (tid == 255) offs[NN] = run;
}

__global__ void fill_csr_kernel(const int* __restrict__ ei, const float* __restrict__ ew,
                                const float* __restrict__ dis, const int* __restrict__ offs,
                                int* __restrict__ cursor, int* __restrict__ csr_src,
                                float* __restrict__ csr_w) {
  int e = blockIdx.x * 256 + threadIdx.x;
  if (e < EE) {
    int row = ei[e], col = ei[EE + e];
    int pos = offs[col] + atomicAdd(&cursor[col], 1);
    csr_src[pos] = row;
    csr_w[pos] = dis[row] * ew[e] * dis[col];
  }
}

// ---------------- weight prepack: fp32 [k][n] -> bf16 MFMA b-frag order ----------------

__global__ void prepack_kernel(const float* __restrict__ convW, unsigned short* __restrict__ Wp) {
  int idx = blockIdx.x * 256 + threadIdx.x;  // 6*8*8*64 = 24576
  int lane = idx & 63;
  int ks = (idx >> 6) & 7;
  int nt = (idx >> 9) & 7;
  int g = idx >> 12;
  const float* W = convW + (size_t)g * 256 * 128;
  int n = nt * 16 + (lane & 15);
  int k0 = ks * 32 + (lane >> 4) * 8;
  unsigned short v[8];
#pragma unroll
  for (int j = 0; j < 8; j++) v[j] = f2bf(W[(size_t)(k0 + j) * 128 + n]);
  *(uint4*)(Wp + (size_t)idx * 8) = *(const uint4*)v;
}

// ---------------- lin_in (bootstrap t=0 only) ----------------

__global__ __launch_bounds__(256) void lin_in_kernel(const float* __restrict__ x_seq,
                                                     const float* __restrict__ W,
                                                     const float* __restrict__ b,
                                                     unsigned short* __restrict__ xt, int t) {
  int idx = blockIdx.x * 256 + threadIdx.x;   // over TOTAL*16
  int row = idx >> 4, fh = idx & 15;          // feats 8fh..8fh+7
  int n = row >> 3, bb = row & 7;
  const float* xp = x_seq + (((size_t)bb * SS + t) * NN + n) * FF;
  float4 a0 = *(const float4*)&b[fh * 8];
  float4 a1 = *(const float4*)&b[fh * 8 + 4];
#pragma unroll
  for (int ff = 0; ff < FF; ff++) {
    float xv = xp[ff];
    float4 w0 = *(const float4*)&W[ff * HH + fh * 8];
    float4 w1 = *(const float4*)&W[ff * HH + fh * 8 + 4];
    a0.x += xv * w0.x; a0.y += xv * w0.y; a0.z += xv * w0.z; a0.w += xv * w0.w;
    a1.x += xv * w1.x; a1.y += xv * w1.y; a1.z += xv * w1.z; a1.w += xv * w1.w;
  }
  uint4 o;
  o.x = (unsigned)f2bf(fmaxf(a0.x, 0.f)) | ((unsigned)f2bf(fmaxf(a0.y, 0.f)) << 16);
  o.y = (unsigned)f2bf(fmaxf(a0.z, 0.f)) | ((unsigned)f2bf(fmaxf(a0.w, 0.f)) << 16);
  o.z = (unsigned)f2bf(fmaxf(a1.x, 0.f)) | ((unsigned)f2bf(fmaxf(a1.y, 0.f)) << 16);
  o.w = (unsigned)f2bf(fmaxf(a1.z, 0.f)) | ((unsigned)f2bf(fmaxf(a1.w, 0.f)) << 16);
  *(uint4*)&xt[(size_t)row * 128 + fh * 8] = o;
}

// ---------------- shared GEMM body (32-row tile, 8 waves) ----------------
// As (32 x 256 bf16, stride 264) staged by caller (caller syncs). MFMA, then
// per-(node,half) absmax computed FROM ACCUMULATORS (shfl + gmax LDS reduce),
// then int8 quantize acc directly -> byte stores to global. gmax = float[32].

template <int MT, int NTW, int HALVES, int NTHREADS>
__device__ __forceinline__ void gemm_body(const unsigned short* As, float* gmax,
                                          const unsigned short* __restrict__ Wp,
                                          signed char* __restrict__ qA,
                                          signed char* __restrict__ qB,
                                          float* __restrict__ sA,
                                          float* __restrict__ sB,
                                          int rowBase, int tid) {
  constexpr int NWAVES = NTHREADS / 64;     // 8
  constexpr int WPG = NWAVES / HALVES;      // waves per half: 4 or 8
  static_assert(MT == 2, "node mapping assumes 32-row tile");
  int wv = tid >> 6, lane = tid & 63;
  int m = lane & 15, q = lane >> 4;
  f32x4 acc[MT][NTW];
#pragma unroll
  for (int i = 0; i < MT; i++)
#pragma unroll
    for (int j = 0; j < NTW; j++) acc[i][j] = (f32x4)(0.0f);
  const unsigned short* wbase = Wp + ((size_t)(wv * NTW) * 8 * 64 + lane) * 8;
#pragma unroll
  for (int ks = 0; ks < 8; ks++) {
    short8 a[MT];
#pragma unroll
    for (int mt = 0; mt < MT; mt++)
      a[mt] = *(const short8*)&As[(mt * 16 + m) * 264 + ks * 32 + q * 8];
#pragma unroll
    for (int nt = 0; nt < NTW; nt++) {
      short8 b = *(const short8*)(wbase + (size_t)(nt * 8 + ks) * 64 * 8);
#pragma unroll
      for (int mt = 0; mt < MT; mt++)
        acc[mt][nt] = __builtin_amdgcn_mfma_f32_16x16x32_bf16(a[mt], b, acc[mt][nt], 0, 0, 0);
    }
  }
  // Per-lane row->node mapping: rows mt*16+q*4+i; node = mt*2 + (q>>1).
  float mxa = 0.f, mxb = 0.f;
#pragma unroll
  for (int nt = 0; nt < NTW; nt++)
#pragma unroll
    for (int i = 0; i < 4; i++) {
      mxa = fmaxf(mxa, fabsf(acc[0][nt][i]));
      mxb = fmaxf(mxb, fabsf(acc[1][nt][i]));
    }
#pragma unroll
  for (int off = 16; off; off >>= 1) {
    mxa = fmaxf(mxa, __shfl_down(mxa, off));
    mxb = fmaxf(mxb, __shfl_down(mxb, off));
  }
  if (lane == 0)  { gmax[wv * 4 + 0] = mxa; gmax[wv * 4 + 2] = mxb; }
  if (lane == 32) { gmax[wv * 4 + 1] = mxa; gmax[wv * 4 + 3] = mxb; }
  __syncthreads();
  // global per-(node,half) scale
  if (tid < 4 * HALVES) {
    int node = (HALVES == 2) ? (tid >> 1) : tid;
    int half = (HALVES == 2) ? (tid & 1) : 0;
    float g = 0.f;
#pragma unroll
    for (int w = 0; w < WPG; w++) g = fmaxf(g, gmax[(half * WPG + w) * 4 + node]);
    float* sp = half ? sB : sA;
    sp[(rowBase >> 3) + node] = g * (1.0f / 127.0f);
  }
  // per-lane inverse scales for its two nodes
  int half = (HALVES == 2) ? (wv / WPG) : 0;
  int qh = q >> 1;
  float ga = 0.f, gb = 0.f;
#pragma unroll
  for (int w = 0; w < WPG; w++) {
    ga = fmaxf(ga, gmax[(half * WPG + w) * 4 + qh]);
    gb = fmaxf(gb, gmax[(half * WPG + w) * 4 + 2 + qh]);
  }
  float invA = (ga > 0.f) ? (127.0f / ga) : 0.f;
  float invB = (gb > 0.f) ? (127.0f / gb) : 0.f;
  // quantize acc directly -> byte stores (rows strided by 128B)
  signed char* qbase = (half ? qB : qA);
#pragma unroll
  for (int mt = 0; mt < MT; mt++) {
    float inv = mt ? invB : invA;
#pragma unroll
    for (int nt = 0; nt < NTW; nt++) {
      int colq = (wv * NTW + nt) * 16 + m - half * 128;
      signed char* dst = qbase + (size_t)(rowBase + mt * 16 + q * 4) * 128 + colq;
#pragma unroll
      for (int i = 0; i < 4; i++) {
        int qv = __float2int_rn(acc[mt][nt][i] * inv);
        dst[(size_t)i * 128] = (signed char)qv;
      }
    }
  }
}

// ---------------- bootstrap GEMM (stages both halves from global) ----------------

template <int NTW, int HALVES>
__global__ __launch_bounds__(512) void gemm_mfma_q(const unsigned short* __restrict__ A1,
                                                   const unsigned short* __restrict__ A2,
                                                   const unsigned short* __restrict__ Wp,
                                                   signed char* __restrict__ qA,
                                                   signed char* __restrict__ qB,
                                                   float* __restrict__ sA,
                                                   float* __restrict__ sB) {
  __shared__ unsigned short As[32 * 264];
  __shared__ float gmax[32];
  int rowBase = blockIdx.x * 32;
  int tid = threadIdx.x;
  for (int c = tid; c < 1024; c += 512) {
    int row = c >> 5; int rest = c & 31; int half = rest >> 4; int sub = rest & 15;
    const unsigned short* src = (half ? A2 : A1) + ((size_t)(rowBase + row) * 128 + sub * 8);
    *(uint4*)&As[row * 264 + half * 128 + sub * 8] = *(const uint4*)src;
  }
  __syncthreads();
  gemm_body<2, NTW, HALVES, 512>(As, gmax, Wp, qA, qB, sA, sB, rowBase, tid);
}

// ---------------- FUSED B/D: gates-gather prologue + candidate GEMM ----------------
// 8 gather units (4 nodes x {r,u}) -> one per wave. rh -> LDS A2; u -> global.
// A1 staged one-uint4-per-thread.

__global__ __launch_bounds__(512, 8) void fused_cand_q(
    const signed char* __restrict__ GqR, const signed char* __restrict__ GqU,
    const float* __restrict__ sR, const float* __restrict__ sU,
    const int* __restrict__ offs, const int* __restrict__ csr_src,
    const float* __restrict__ csr_w, const float* __restrict__ dis,
    const float* __restrict__ bRU, const unsigned short* __restrict__ h,
    unsigned short* __restrict__ u_out,
    const unsigned short* __restrict__ A1, const unsigned short* __restrict__ Wp,
    signed char* __restrict__ Cq, float* __restrict__ sC) {
  __shared__ unsigned short As[32 * 264];
  __shared__ float gmax[32];
  int tid = threadIdx.x;
  int wv = tid >> 6, lane = tid & 63;
  int rowBase = blockIdx.x * 32, gn0 = rowBase >> 3;
  int bb = lane >> 3, fo = (lane & 7) << 4;
  int node8 = wv >> 1, half = wv & 1;
  int n = gn0 + node8;
  int e0 = offs[n], e1 = offs[n + 1];   // metadata first (overlaps staging)
  // stage A1 (xin) into cols 0..127 — one uint4 per thread
  {
    int row = tid >> 4, sub = tid & 15;
    *(uint4*)&As[row * 264 + sub * 8] =
        *(const uint4*)&A1[(size_t)(rowBase + row) * 128 + sub * 8];
  }
  float acc[16];
  gather_accum(half ? GqU : GqR, half ? sU : sR, e0, e1, csr_src, csr_w, dis, n, bb, fo, acc);
  const float* bias = bRU + half * 128 + fo;
  size_t rowSelf = ((size_t)n << 3) + bb;
  if (half == 0) {
    int lr = node8 * 8 + bb;
#pragma unroll
    for (int jj = 0; jj < 2; jj++) {
      uint4 hq = *(const uint4*)&h[rowSelf * 128 + fo + 8 * jj];
      float hv[8];
      hv[0] = bflo(hq.x); hv[1] = bfhi(hq.x); hv[2] = bflo(hq.y); hv[3] = bfhi(hq.y);
      hv[4] = bflo(hq.z); hv[5] = bfhi(hq.z); hv[6] = bflo(hq.w); hv[7] = bfhi(hq.w);
      unsigned ow[4];
#pragma unroll
      for (int d = 0; d < 4; d++) {
        float s0 = 1.0f / (1.0f + __expf(-(acc[8 * jj + 2 * d]     + bias[8 * jj + 2 * d])));
        float s1 = 1.0f / (1.0f + __expf(-(acc[8 * jj + 2 * d + 1] + bias[8 * jj + 2 * d + 1])));
        ow[d] = (unsigned)f2bf(s0 * hv[2 * d]) | ((unsigned)f2bf(s1 * hv[2 * d + 1]) << 16);
      }
      uint4 o; o.x = ow[0]; o.y = ow[1]; o.z = ow[2]; o.w = ow[3];
      *(uint4*)&As[lr * 264 + 128 + fo + 8 * jj] = o;
    }
  } else {
#pragma unroll
    for (int jj = 0; jj < 2; jj++) {
      unsigned ow[4];
#pragma unroll
      for (int d = 0; d < 4; d++) {
        float s0 = 1.0f / (1.0f + __expf(-(acc[8 * jj + 2 * d]     + bias[8 * jj + 2 * d])));
        float s1 = 1.0f / (1.0f + __expf(-(acc[8 * jj + 2 * d + 1] + bias[8 * jj + 2 * d + 1])));
        ow[d] = (unsigned)f2bf(s0) | ((unsigned)f2bf(s1) << 16);
      }
      uint4 o; o.x = ow[0]; o.y = ow[1]; o.z = ow[2]; o.w = ow[3];
      *(uint4*)&u_out[rowSelf * 128 + fo + 8 * jj] = o;
    }
  }
  __syncthreads();
  gemm_body<2, 1, 1, 512>(As, gmax, Wp, Cq, Cq, sC, sC, rowBase, tid);
}

// ---------------- FUSED C: cand-gather + GRU prologue + gates GEMM ----------------
// Waves 0-3: full-degree cand-gather node wv, GRU (u from global) -> h + LDS A1.
// Waves 4-7: stage A2 (other layer's state).

__global__ __launch_bounds__(512, 8) void fused_gates_q(
    const signed char* __restrict__ Cq, const float* __restrict__ sC,
    const int* __restrict__ offs, const int* __restrict__ csr_src,
    const float* __restrict__ csr_w, const float* __restrict__ dis,
    const float* __restrict__ bC, const unsigned short* __restrict__ u_in,
    unsigned short* __restrict__ h_io,
    const unsigned short* __restrict__ A2src, const unsigned short* __restrict__ Wp,
    signed char* __restrict__ GqRo, signed char* __restrict__ GqUo,
    float* __restrict__ sRo, float* __restrict__ sUo) {
  __shared__ unsigned short As[32 * 264];
  __shared__ float gmax[32];
  int tid = threadIdx.x;
  int wv = tid >> 6, lane = tid & 63;
  int rowBase = blockIdx.x * 32, gn0 = rowBase >> 3;
  int bb = lane >> 3, fo = (lane & 7) << 4;
  if (wv >= 4) {
    int t2 = tid - 256;
    for (int c = t2; c < 512; c += 256) {
      int row = c >> 4, sub = c & 15;
      *(uint4*)&As[row * 264 + 128 + sub * 8] =
          *(const uint4*)&A2src[(size_t)(rowBase + row) * 128 + sub * 8];
    }
  } else {
    int node8 = wv;
    int n = gn0 + node8;
    int e0 = offs[n], e1 = offs[n + 1];
    float acc[16];
    gather_accum(Cq, sC, e0, e1, csr_src, csr_w, dis, n, bb, fo, acc);
    size_t rowSelf = ((size_t)n << 3) + bb;
    uint4 o0, o1;
    gru_combine_store(acc, bC + fo, u_in, h_io, rowSelf, fo, o0, o1);
    int lr = node8 * 8 + bb;
    *(uint4*)&As[lr * 264 + fo] = o0;
    *(uint4*)&As[lr * 264 + fo + 8] = o1;
  }
  __syncthreads();
  gemm_body<2, 2, 2, 512>(As, gmax, Wp, GqRo, GqUo, sRo, sUo, rowBase, tid);
}

// ---------------- FUSED E: cand-gather h1 GRU + lin_in(t+1) + gates0 GEMM ----------
// Waves 0-3: cand-gather node wv, GRU (u from global) -> h1 global.
// Waves 4-7: stage A2 (h0) + lin_in(t+1) -> LDS A1 + global xt.

__global__ __launch_bounds__(512, 8) void fused_gates_lin_q(
    const signed char* __restrict__ Cq, const float* __restrict__ sC,
    const int* __restrict__ offs, const int* __restrict__ csr_src,
    const float* __restrict__ csr_w, const float* __restrict__ dis,
    const float* __restrict__ bC, const unsigned short* __restrict__ u_in,
    unsigned short* __restrict__ h_io,
    const float* __restrict__ x_seq, const float* __restrict__ Win,
    const float* __restrict__ bin, unsigned short* __restrict__ xt_out,
    const unsigned short* __restrict__ A2src, const unsigned short* __restrict__ Wp,
    signed char* __restrict__ GqRo, signed char* __restrict__ GqUo,
    float* __restrict__ sRo, float* __restrict__ sUo, int t_next) {
  __shared__ unsigned short As[32 * 264];
  __shared__ float gmax[32];
  int tid = threadIdx.x;
  int wv = tid >> 6, lane = tid & 63;
  int rowBase = blockIdx.x * 32, gn0 = rowBase >> 3;
  int bb = lane >> 3, fo = (lane & 7) << 4;
  if (wv < 4) {
    int node8 = wv;
    int n = gn0 + node8;
    int e0 = offs[n], e1 = offs[n + 1];
    float acc[16];
    gather_accum(Cq, sC, e0, e1, csr_src, csr_w, dis, n, bb, fo, acc);
    size_t rowSelf = ((size_t)n << 3) + bb;
    uint4 o0, o1;
    gru_combine_store(acc, bC + fo, u_in, h_io, rowSelf, fo, o0, o1);
  } else {
    int t2 = tid - 256;
    // stage A2 (h0) into cols 128..255
    for (int c = t2; c < 512; c += 256) {
      int row = c >> 4, sub = c & 15;
      *(uint4*)&As[row * 264 + 128 + sub * 8] =
          *(const uint4*)&A2src[(size_t)(rowBase + row) * 128 + sub * 8];
    }
    // lin_in for t_next: 32 rows x 16 fh-units -> LDS cols 0..127 + global xt
    for (int c = t2; c < 512; c += 256) {
      int row = c >> 4, fh = c & 15;
      int grow = rowBase + row;
      int n2 = grow >> 3, bbv = grow & 7;
      const float* xp = x_seq + (((size_t)bbv * SS + t_next) * NN + n2) * FF;
      float4 a0 = *(const float4*)&bin[fh * 8];
      float4 a1 = *(const float4*)&bin[fh * 8 + 4];
#pragma unroll
      for (int ff = 0; ff < FF; ff++) {
        float xv = xp[ff];
        float4 w0 = *(const float4*)&Win[ff * HH + fh * 8];
        float4 w1 = *(const float4*)&Win[ff * HH + fh * 8 + 4];
        a0.x += xv * w0.x; a0.y += xv * w0.y; a0.z += xv * w0.z; a0.w += xv * w0.w;
        a1.x += xv * w1.x; a1.y += xv * w1.y; a1.z += xv * w1.z; a1.w += xv * w1.w;
      }
      uint4 o;
      o.x = (unsigned)f2bf(fmaxf(a0.x, 0.f)) | ((unsigned)f2bf(fmaxf(a0.y, 0.f)) << 16);
      o.y = (unsigned)f2bf(fmaxf(a0.z, 0.f)) | ((unsigned)f2bf(fmaxf(a0.w, 0.f)) << 16);
      o.z = (unsigned)f2bf(fmaxf(a1.x, 0.f)) | ((unsigned)f2bf(fmaxf(a1.y, 0.f)) << 16);
      o.w = (unsigned)f2bf(fmaxf(a1.z, 0.f)) | ((unsigned)f2bf(fmaxf(a1.w, 0.f)) << 16);
      *(uint4*)&As[row * 264 + fh * 8] = o;
      *(uint4*)&xt_out[(size_t)grow * 128 + fh * 8] = o;
    }
  }
  __syncthreads();
  gemm_body<2, 2, 2, 512>(As, gmax, Wp, GqRo, GqUo, sRo, sUo, rowBase, tid);
}

// ---------------- final candidate aggregation + GRU update (t = S-1, layer 1) --------

__global__ __launch_bounds__(256) void scatter_c_update_q(
    const signed char* __restrict__ Cq, const float* __restrict__ sC,
    const int* __restrict__ offs, const int* __restrict__ csr_src,
    const float* __restrict__ csr_w, const float* __restrict__ dis,
    const float* __restrict__ bC, const unsigned short* __restrict__ u,
    unsigned short* __restrict__ h) {
  int tid = threadIdx.x;
  int wv = tid >> 6, lane = tid & 63;
  int n = blockIdx.x * 4 + wv;
  int bb = lane >> 3;
  int fo = (lane & 7) << 4;
  int e0 = offs[n], e1 = offs[n + 1];
  float acc[16];
  gather_accum(Cq, sC, e0, e1, csr_src, csr_w, dis, n, bb, fo, acc);
  size_t rowSelf = (size_t)(n << 3) + bb;
  uint4 o0, o1;
  gru_combine_store(acc, bC + fo, u, h, rowSelf, fo, o0, o1);
}

// ---------------- BatchNorm stats ----------------

__global__ __launch_bounds__(256) void bn_stats_kernel(const unsigned short* __restrict__ h,
                                                       float* __restrict__ sums) {
  __shared__ float ls[512];
  int tid = threadIdx.x;
  float s = 0.f, sq = 0.f;
  for (size_t idx = (size_t)blockIdx.x * 256 + tid; idx < (size_t)TOTAL * HH;
       idx += (size_t)gridDim.x * 256) {
    float v = bf2f(h[idx]);
    s += v; sq += v * v;
  }
  ls[tid] = s; ls[256 + tid] = sq;
  __syncthreads();
  if (tid < 128) {
    atomicAdd(&sums[tid], ls[tid] + ls[tid + 128]);
    atomicAdd(&sums[128 + tid], ls[256 + tid] + ls[256 + tid + 128]);
  }
}

// ---------------- fused BN -> relu -> lin_out -> log_softmax ----------------

__global__ __launch_bounds__(256) void final_kernel(const unsigned short* __restrict__ h,
                                                    const float* __restrict__ sums,
                                                    const float* __restrict__ gamma,
                                                    const float* __restrict__ beta,
                                                    const float* __restrict__ Wout,
                                                    const float* __restrict__ bout,
                                                    float* __restrict__ out) {
  int wid = threadIdx.x >> 6, lane = threadIdx.x & 63;
  int row = blockIdx.x * 4 + wid; // node-row (n*8+bb order)
  if (row >= TOTAL) return;
  const float inv = 1.0f / (float)TOTAL;
  float p0 = 0.f, p1 = 0.f, p2 = 0.f, p3 = 0.f;
#pragma unroll
  for (int jj = 0; jj < 2; jj++) {
    int j = lane + jj * 64;
    float mean = sums[j] * inv;
    float var = sums[128 + j] * inv - mean * mean;
    float hn = (bf2f(h[(size_t)row * HH + j]) - mean) * rsqrtf(var + 1e-5f) * gamma[j] + beta[j];
    hn = fmaxf(hn, 0.0f);
    p0 += hn * Wout[j * 4 + 0];
    p1 += hn * Wout[j * 4 + 1];
    p2 += hn * Wout[j * 4 + 2];
    p3 += hn * Wout[j * 4 + 3];
  }
  for (int off = 32; off; off >>= 1) {
    p0 += __shfl_down(p0, off);
    p1 += __shfl_down(p1, off);
    p2 += __shfl_down(p2, off);
    p3 += __shfl_down(p3, off);
  }
  if (lane == 0) {
    p0 += bout[0]; p1 += bout[1]; p2 += bout[2]; p3 += bout[3];
    float m = fmaxf(fmaxf(p0, p1), fmaxf(p2, p3));
    float e = __expf(p0 - m) + __expf(p1 - m) + __expf(p2 - m) + __expf(p3 - m);
    float lse = m + __logf(e);
    int bb = row & 7, n = row >> 3;
    float* o = out + ((size_t)bb * NN + n) * 4;
    o[0] = p0 - lse; o[1] = p1 - lse; o[2] = p2 - lse; o[3] = p3 - lse;
  }
}

// ---------------- launcher ----------------

extern "C" void kernel_launch(void* const* d_in, const int* in_sizes, int n_in,
                              void* d_out, int out_size, void* d_ws, size_t ws_size,
                              hipStream_t stream) {
  const float* x_seq = (const float*)d_in[0];
  const int* ei      = (const int*)d_in[1];
  const float* ew    = (const float*)d_in[2];
  const float* Win   = (const float*)d_in[3];
  const float* bin   = (const float*)d_in[4];
  const float* convW = (const float*)d_in[5];
  const float* convB = (const float*)d_in[6];
  const float* gamma = (const float*)d_in[7];
  const float* beta  = (const float*)d_in[8];
  const float* Wout  = (const float*)d_in[9];
  const float* bout  = (const float*)d_in[10];
  float* out = (float*)d_out;

  char* ws = (char*)d_ws;
  size_t off = 0;
  auto alloc = [&](size_t bytes) {
    void* p = ws + off;
    off += (bytes + 1023) & ~(size_t)1023;
    return p;
  };
  float* deg     = (float*)alloc(NN * 4);
  float* dis     = (float*)alloc(NN * 4);
  int*   cnt     = (int*)alloc(NN * 4);
  int*   offs    = (int*)alloc((NN + 1) * 4);
  int*   cursor  = (int*)alloc(NN * 4);
  int*   csr_src = (int*)alloc(EE * 4);
  float* csr_w   = (float*)alloc(EE * 4);
  float* sums    = (float*)alloc(256 * 4);
  float* sR      = (float*)alloc(NN * 4);
  float* sU      = (float*)alloc(NN * 4);
  float* sC      = (float*)alloc(NN * 4);
  unsigned short* Wp = (unsigned short*)alloc(6 * 32768 * 2);  // packed conv weights
  const size_t NH = (size_t)TOTAL * HH; // 5,120,000
  unsigned short* h0 = (unsigned short*)alloc(NH * 2);
  unsigned short* h1 = (unsigned short*)alloc(NH * 2);
  unsigned short* xt = (unsigned short*)alloc(NH * 2);
  unsigned short* ub = (unsigned short*)alloc(NH * 2);
  signed char* GqR = (signed char*)alloc(NH);   // int8 messages
  signed char* GqU = (signed char*)alloc(NH);
  signed char* Cq  = (signed char*)alloc(NH);   // DEDICATED (no alias with GqR!)

  hipMemsetAsync(deg, 0, NN * 4, stream);
  hipMemsetAsync(cnt, 0, NN * 4, stream);
  hipMemsetAsync(cursor, 0, NN * 4, stream);
  hipMemsetAsync(sums, 0, 256 * 4, stream);
  hipMemsetAsync(h0, 0, NH * 2, stream);
  hipMemsetAsync(h1, 0, NH * 2, stream);

  deg_cnt_kernel<<<(EE + 255) / 256, 256, 0, stream>>>(ei, ew, deg, cnt);
  dis_kernel<<<(NN + 255) / 256, 256, 0, stream>>>(deg, dis);
  scan_kernel<<<1, 256, 0, stream>>>(cnt, offs);
  fill_csr_kernel<<<(EE + 255) / 256, 256, 0, stream>>>(ei, ew, dis, offs, cursor, csr_src, csr_w);
  prepack_kernel<<<24576 / 256, 256, 0, stream>>>(convW, Wp);

  const unsigned short* Wg0 = Wp;
  const unsigned short* Wc0 = Wp + (size_t)2 * 32768;
  const unsigned short* Wg1 = Wp + (size_t)3 * 32768;
  const unsigned short* Wc1 = Wp + (size_t)5 * 32768;
  const float* bRU0 = convB;
  const float* bC0  = convB + 2 * HH;
  const float* bRU1 = convB + 3 * HH;
  const float* bC1  = convB + 5 * HH;

  // bootstrap: xt(t=0), gates0(t=0)
  lin_in_kernel<<<TOTAL * 16 / 256, 256, 0, stream>>>(x_seq, Win, bin, xt, 0);
  gemm_mfma_q<2, 2><<<TOTAL / 32, 512, 0, stream>>>(xt, h0, Wg0, GqR, GqU, sR, sU);

  for (int t = 0; t < SS; t++) {
    // B: gates0-gather -> rh0(LDS), u0 -> cand0 GEMM -> Cq
    fused_cand_q<<<TOTAL / 32, 512, 0, stream>>>(GqR, GqU, sR, sU, offs, csr_src, csr_w,
                                                 dis, bRU0, h0, ub, xt, Wc0, Cq, sC);
    // C: cand0-gather -> h0 update (global+LDS A1) -> gates1 GEMM -> GqR/GqU
    fused_gates_q<<<TOTAL / 32, 512, 0, stream>>>(Cq, sC, offs, csr_src, csr_w, dis,
                                                  bC0, ub, h0, h1, Wg1, GqR, GqU, sR, sU);
    // D: gates1-gather -> rh1(LDS), u1 -> cand1 GEMM -> Cq
    fused_cand_q<<<TOTAL / 32, 512, 0, stream>>>(GqR, GqU, sR, sU, offs, csr_src, csr_w,
                                                 dis, bRU1, h1, ub, h0, Wc1, Cq, sC);
    // E: cand1-gather -> h1 update; lin_in(t+1) -> xt; gates0 GEMM -> GqR/GqU
    if (t < SS - 1) {
      fused_gates_lin_q<<<TOTAL / 32, 512, 0, stream>>>(Cq, sC, offs, csr_src, csr_w, dis,
                                                        bC1, ub, h1, x_seq, Win, bin, xt,
                                                        h0, Wg0, GqR, GqU, sR, sU, t + 1);
    } else {
      scatter_c_update_q<<<NN / 4, 256, 0, stream>>>(Cq, sC, offs, csr_src, csr_w,
                                                     dis, bC1, ub, h1);
    }
  }

  bn_stats_kernel<<<256, 256, 0, stream>>>(h1, sums);
  final_kernel<<<TOTAL / 4, 256, 0, stream>>>(h1, sums, gamma, beta, Wout, bout, out);
}

// Round 12
// 1507.852 us; speedup vs baseline: 3.9000x; 1.2990x over previous
//
#include <hip/hip_runtime.h>
#include <cstdint>
#include <cstddef>

#define NN 5000     // nodes per batch block
#define EE 40000    // edges per batch block
#define BATCH 8
#define SS 12
#define FF 16
#define HH 128
#define TOTAL 40000 // BATCH*NN
#define CC 4

// Layout: per-row state arrays use row = n*8 + bb (batch-interleaved). Gather-only
// message matrices are INT8 with one fp32 scale per source node per matrix.
//
// Fused schedule (R9 CHAMPION, restored): B cand0-GEMM, C gates1-GEMM,
// D cand1-GEMM, E gates0-GEMM(+lin_in t+1); each kernel's PROLOGUE gathers the
// previous GEMM's messages for its own 4 nodes. 32-row tiles, 512 threads,
// 4 blk/CU. Lane-parallel gather metadata + 4-wide independent Gq row issue.
//
// Refuted levers (kept for the record):
//  - R10 persistent cooperative loop: grid.sync across 8 non-coherent XCD L2s
//    cost 3.9x (VALU 6%, HBM 9% at 99% occupancy = resident but spinning).
//  - R11 8-wide gather issue: qv[8] exceeded the 32-VGPR allocation under
//    launch_bounds(512,8) -> scratch spills (+39MB FETCH AND WRITE per
//    dispatch, the symmetric-spill signature). 4-wide fits; 8 does not.
//  - R6 u-gather-in-C/E: +13MB random FETCH beat the 10MB contiguous u trip.
//  - R4 edge-split pairs: cut MLP without shortening latency rounds.
//  - R7 direct-quant epilogue: neutral (kept: less LDS, one barrier fewer).
//
// CORRECTNESS (G16): Cq dedicated (not aliasing GqR) — cross-block race at
// grid > co-residency, proven in R2.

typedef __attribute__((ext_vector_type(8))) short short8;   // 8 bf16 (4 VGPRs)
typedef __attribute__((ext_vector_type(4))) float f32x4;    // 4 fp32

__device__ __forceinline__ unsigned short f2bf(float f) {
  union { float f; unsigned u; } v; v.f = f;
  unsigned r = v.u + 0x7fff + ((v.u >> 16) & 1);  // RTNE
  return (unsigned short)(r >> 16);
}
__device__ __forceinline__ float bf2f(unsigned short b) {
  union { unsigned u; float f; } v; v.u = ((unsigned)b) << 16;
  return v.f;
}
__device__ __forceinline__ float bflo(unsigned v) {
  union { unsigned u; float f; } x; x.u = v << 16; return x.f;
}
__device__ __forceinline__ float bfhi(unsigned v) {
  union { unsigned u; float f; } x; x.u = v & 0xffff0000u; return x.f;
}
// acc[0..15] += ws * (int8x16 from qv)
__device__ __forceinline__ void qfma16(float* acc, uint4 qv, float ws) {
  unsigned wd[4] = {qv.x, qv.y, qv.z, qv.w};
#pragma unroll
  for (int d = 0; d < 4; d++) {
#pragma unroll
    for (int k = 0; k < 4; k++) {
      int q = (int)((signed char)(wd[d] >> (8 * k)));
      acc[d * 4 + k] += ws * (float)q;
    }
  }
}

// Full-degree gather: one wave owns one (node, matrix) unit.
// lane -> (bb = lane>>3, 16 feats at (lane&7)*16). acc[16] out.
// Lane-parallel metadata: lane l loads csr_src/csr_w[e0+l] and sc[idx] in ONE
// round; per-edge broadcast via __shfl; Gq row loads independent, 4-wide
// (8-wide spills past the 32-VGPR allocation — R11).
__device__ __forceinline__ void gather_accum(const signed char* __restrict__ Gq,
                                             const float* __restrict__ sc,
                                             int e0, int e1,
                                             const int* __restrict__ csr_src,
                                             const float* __restrict__ csr_w,
                                             const float* __restrict__ dis,
                                             int n, int bb, int fo, float* acc) {
  int lane = (bb << 3) | (fo >> 4);
  int deg = e1 - e0;
  int myi = 0; float myw = 0.f;
  if (lane < deg) {
    myi = csr_src[e0 + lane];
    myw = csr_w[e0 + lane];
  }
  float mys = sc[myi];                 // lane-parallel scale gather (idx 0 if idle)
  float sn = dis[n]; sn *= sn;
  size_t rowSelf = (size_t)(n << 3) + bb;
#pragma unroll
  for (int k = 0; k < 16; k++) acc[k] = 0.f;
  {
    float ws = sn * sc[n];
    uint4 qv = *(const uint4*)&Gq[rowSelf * 128 + fo];
    qfma16(acc, qv, ws);
  }
  int dmax = deg < 64 ? deg : 64;
  int e = 0;
  for (; e + 3 < dmax; e += 4) {
    int s0 = __shfl(myi, e),     s1 = __shfl(myi, e + 1);
    int s2 = __shfl(myi, e + 2), s3 = __shfl(myi, e + 3);
    uint4 qa = *(const uint4*)&Gq[(((size_t)s0 << 3) + bb) * 128 + fo];
    uint4 qb = *(const uint4*)&Gq[(((size_t)s1 << 3) + bb) * 128 + fo];
    uint4 qc = *(const uint4*)&Gq[(((size_t)s2 << 3) + bb) * 128 + fo];
    uint4 qd = *(const uint4*)&Gq[(((size_t)s3 << 3) + bb) * 128 + fo];
    float w0 = __shfl(myw, e)     * __shfl(mys, e);
    float w1 = __shfl(myw, e + 1) * __shfl(mys, e + 1);
    float w2 = __shfl(myw, e + 2) * __shfl(mys, e + 2);
    float w3 = __shfl(myw, e + 3) * __shfl(mys, e + 3);
    qfma16(acc, qa, w0);
    qfma16(acc, qb, w1);
    qfma16(acc, qc, w2);
    qfma16(acc, qd, w3);
  }
  for (; e < dmax; e++) {
    int s0 = __shfl(myi, e);
    float w0 = __shfl(myw, e) * __shfl(mys, e);
    uint4 qa = *(const uint4*)&Gq[(((size_t)s0 << 3) + bb) * 128 + fo];
    qfma16(acc, qa, w0);
  }
  // rare tail: deg > 64 (scalar path, keeps correctness for any graph)
  for (int ee = e0 + 64; ee < e1; ee++) {
    int s0 = csr_src[ee];
    float w0 = csr_w[ee] * sc[s0];
    uint4 qa = *(const uint4*)&Gq[(((size_t)s0 << 3) + bb) * 128 + fo];
    qfma16(acc, qa, w0);
  }
}

// GRU combine, 8-element chunks (low register pressure), u from global bf16:
// h_new = u*h + (1-u)*tanh(acc+b); writes h back to global; o0/o1 packed rows.
__device__ __forceinline__ void gru_combine_store(const float* acc, const float* bp,
                                                  const unsigned short* __restrict__ u_in,
                                                  unsigned short* __restrict__ h_io,
                                                  size_t rowSelf, int fo,
                                                  uint4& o0, uint4& o1) {
  uint4 oo[2];
#pragma unroll
  for (int jj = 0; jj < 2; jj++) {
    uint4 uq = *(const uint4*)&u_in[rowSelf * 128 + fo + 8 * jj];
    uint4 hq = *(const uint4*)&h_io[rowSelf * 128 + fo + 8 * jj];
    float uv[8], hv[8];
    uv[0] = bflo(uq.x); uv[1] = bfhi(uq.x); uv[2] = bflo(uq.y); uv[3] = bfhi(uq.y);
    uv[4] = bflo(uq.z); uv[5] = bfhi(uq.z); uv[6] = bflo(uq.w); uv[7] = bfhi(uq.w);
    hv[0] = bflo(hq.x); hv[1] = bfhi(hq.x); hv[2] = bflo(hq.y); hv[3] = bfhi(hq.y);
    hv[4] = bflo(hq.z); hv[5] = bfhi(hq.z); hv[6] = bflo(hq.w); hv[7] = bfhi(hq.w);
    unsigned ow[4];
#pragma unroll
    for (int d = 0; d < 4; d++) {
      float v0 = acc[8 * jj + 2 * d]     + bp[8 * jj + 2 * d];
      float v1 = acc[8 * jj + 2 * d + 1] + bp[8 * jj + 2 * d + 1];
      float c0 = 1.0f - 2.0f / (__expf(2.0f * v0) + 1.0f);  // tanh
      float c1 = 1.0f - 2.0f / (__expf(2.0f * v1) + 1.0f);
      float n0 = uv[2 * d] * hv[2 * d] + (1.0f - uv[2 * d]) * c0;
      float n1 = uv[2 * d + 1] * hv[2 * d + 1] + (1.0f - uv[2 * d + 1]) * c1;
      ow[d] = (unsigned)f2bf(n0) | ((unsigned)f2bf(n1) << 16);
    }
    oo[jj].x = ow[0]; oo[jj].y = ow[1]; oo[jj].z = ow[2]; oo[jj].w = ow[3];
    *(uint4*)&h_io[rowSelf * 128 + fo + 8 * jj] = oo[jj];
  }
  o0 = oo[0]; o1 = oo[1];
}

// ---------------- graph preprocessing (once per launch) ----------------

__global__ void deg_cnt_kernel(const int* __restrict__ ei, const float* __restrict__ ew,
                               float* __restrict__ deg, int* __restrict__ cnt) {
  int e = blockIdx.x * 256 + threadIdx.x;
  if (e < EE) {
    int col = ei[EE + e];
    atomicAdd(&deg[col], ew[e]);
    atomicAdd(&cnt[col], 1);
  }
}

__global__ void dis_kernel(const float* __restrict__ deg, float* __restrict__ dis) {
  int n = blockIdx.x * 256 + threadIdx.x;
  if (n < NN) dis[n] = rsqrtf(deg[n] + 1.0f);  // +1: self-loop weight
}

__global__ void scan_kernel(const int* __restrict__ cnt, int* __restrict__ offs) {
  __shared__ int part[256];
  const int CH = (NN + 255) / 256; // 20
  int tid = threadIdx.x;
  int base = tid * CH;
  int s = 0;
  for (int i = 0; i < CH; i++) { int idx = base + i; if (idx < NN) s += cnt[idx]; }
  part[tid] = s;
  __syncthreads();
  for (int off = 1; off < 256; off <<= 1) {
    int v = (tid >= off) ? part[tid - off] : 0;
    __syncthreads();
    part[tid] += v;
    __syncthreads();
  }
  int run = (tid == 0) ? 0 : part[tid - 1];
  for (int i = 0; i < CH; i++) {
    int idx = base + i;
    if (idx < NN) { offs[idx] = run; run += cnt[idx]; }
  }
  if (tid == 255) offs[NN] = run;
}

__global__ void fill_csr_kernel(const int* __restrict__ ei, const float* __restrict__ ew,
                                const float* __restrict__ dis, const int* __restrict__ offs,
                                int* __restrict__ cursor, int* __restrict__ csr_src,
                                float* __restrict__ csr_w) {
  int e = blockIdx.x * 256 + threadIdx.x;
  if (e < EE) {
    int row = ei[e], col = ei[EE + e];
    int pos = offs[col] + atomicAdd(&cursor[col], 1);
    csr_src[pos] = row;
    csr_w[pos] = dis[row] * ew[e] * dis[col];
  }
}

// ---------------- weight prepack: fp32 [k][n] -> bf16 MFMA b-frag order ----------------

__global__ void prepack_kernel(const float* __restrict__ convW, unsigned short* __restrict__ Wp) {
  int idx = blockIdx.x * 256 + threadIdx.x;  // 6*8*8*64 = 24576
  int lane = idx & 63;
  int ks = (idx >> 6) & 7;
  int nt = (idx >> 9) & 7;
  int g = idx >> 12;
  const float* W = convW + (size_t)g * 256 * 128;
  int n = nt * 16 + (lane & 15);
  int k0 = ks * 32 + (lane >> 4) * 8;
  unsigned short v[8];
#pragma unroll
  for (int j = 0; j < 8; j++) v[j] = f2bf(W[(size_t)(k0 + j) * 128 + n]);
  *(uint4*)(Wp + (size_t)idx * 8) = *(const uint4*)v;
}

// ---------------- lin_in (bootstrap t=0 only) ----------------

__global__ __launch_bounds__(256) void lin_in_kernel(const float* __restrict__ x_seq,
                                                     const float* __restrict__ W,
                                                     const float* __restrict__ b,
                                                     unsigned short* __restrict__ xt, int t) {
  int idx = blockIdx.x * 256 + threadIdx.x;   // over TOTAL*16
  int row = idx >> 4, fh = idx & 15;          // feats 8fh..8fh+7
  int n = row >> 3, bb = row & 7;
  const float* xp = x_seq + (((size_t)bb * SS + t) * NN + n) * FF;
  float4 a0 = *(const float4*)&b[fh * 8];
  float4 a1 = *(const float4*)&b[fh * 8 + 4];
#pragma unroll
  for (int ff = 0; ff < FF; ff++) {
    float xv = xp[ff];
    float4 w0 = *(const float4*)&W[ff * HH + fh * 8];
    float4 w1 = *(const float4*)&W[ff * HH + fh * 8 + 4];
    a0.x += xv * w0.x; a0.y += xv * w0.y; a0.z += xv * w0.z; a0.w += xv * w0.w;
    a1.x += xv * w1.x; a1.y += xv * w1.y; a1.z += xv * w1.z; a1.w += xv * w1.w;
  }
  uint4 o;
  o.x = (unsigned)f2bf(fmaxf(a0.x, 0.f)) | ((unsigned)f2bf(fmaxf(a0.y, 0.f)) << 16);
  o.y = (unsigned)f2bf(fmaxf(a0.z, 0.f)) | ((unsigned)f2bf(fmaxf(a0.w, 0.f)) << 16);
  o.z = (unsigned)f2bf(fmaxf(a1.x, 0.f)) | ((unsigned)f2bf(fmaxf(a1.y, 0.f)) << 16);
  o.w = (unsigned)f2bf(fmaxf(a1.z, 0.f)) | ((unsigned)f2bf(fmaxf(a1.w, 0.f)) << 16);
  *(uint4*)&xt[(size_t)row * 128 + fh * 8] = o;
}

// ---------------- shared GEMM body (32-row tile, 8 waves) ----------------
// As (32 x 256 bf16, stride 264) staged by caller (caller syncs). MFMA, then
// per-(node,half) absmax computed FROM ACCUMULATORS (shfl + gmax LDS reduce),
// then int8 quantize acc directly -> byte stores to global. gmax = float[32].

template <int MT, int NTW, int HALVES, int NTHREADS>
__device__ __forceinline__ void gemm_body(const unsigned short* As, float* gmax,
                                          const unsigned short* __restrict__ Wp,
                                          signed char* __restrict__ qA,
                                          signed char* __restrict__ qB,
                                          float* __restrict__ sA,
                                          float* __restrict__ sB,
                                          int rowBase, int tid) {
  constexpr int NWAVES = NTHREADS / 64;     // 8
  constexpr int WPG = NWAVES / HALVES;      // waves per half: 4 or 8
  static_assert(MT == 2, "node mapping assumes 32-row tile");
  int wv = tid >> 6, lane = tid & 63;
  int m = lane & 15, q = lane >> 4;
  f32x4 acc[MT][NTW];
#pragma unroll
  for (int i = 0; i < MT; i++)
#pragma unroll
    for (int j = 0; j < NTW; j++) acc[i][j] = (f32x4)(0.0f);
  const unsigned short* wbase = Wp + ((size_t)(wv * NTW) * 8 * 64 + lane) * 8;
#pragma unroll
  for (int ks = 0; ks < 8; ks++) {
    short8 a[MT];
#pragma unroll
    for (int mt = 0; mt < MT; mt++)
      a[mt] = *(const short8*)&As[(mt * 16 + m) * 264 + ks * 32 + q * 8];
#pragma unroll
    for (int nt = 0; nt < NTW; nt++) {
      short8 b = *(const short8*)(wbase + (size_t)(nt * 8 + ks) * 64 * 8);
#pragma unroll
      for (int mt = 0; mt < MT; mt++)
        acc[mt][nt] = __builtin_amdgcn_mfma_f32_16x16x32_bf16(a[mt], b, acc[mt][nt], 0, 0, 0);
    }
  }
  // Per-lane row->node mapping: rows mt*16+q*4+i; node = mt*2 + (q>>1).
  float mxa = 0.f, mxb = 0.f;
#pragma unroll
  for (int nt = 0; nt < NTW; nt++)
#pragma unroll
    for (int i = 0; i < 4; i++) {
      mxa = fmaxf(mxa, fabsf(acc[0][nt][i]));
      mxb = fmaxf(mxb, fabsf(acc[1][nt][i]));
    }
#pragma unroll
  for (int off = 16; off; off >>= 1) {
    mxa = fmaxf(mxa, __shfl_down(mxa, off));
    mxb = fmaxf(mxb, __shfl_down(mxb, off));
  }
  if (lane == 0)  { gmax[wv * 4 + 0] = mxa; gmax[wv * 4 + 2] = mxb; }
  if (lane == 32) { gmax[wv * 4 + 1] = mxa; gmax[wv * 4 + 3] = mxb; }
  __syncthreads();
  // global per-(node,half) scale
  if (tid < 4 * HALVES) {
    int node = (HALVES == 2) ? (tid >> 1) : tid;
    int half = (HALVES == 2) ? (tid & 1) : 0;
    float g = 0.f;
#pragma unroll
    for (int w = 0; w < WPG; w++) g = fmaxf(g, gmax[(half * WPG + w) * 4 + node]);
    float* sp = half ? sB : sA;
    sp[(rowBase >> 3) + node] = g * (1.0f / 127.0f);
  }
  // per-lane inverse scales for its two nodes
  int half = (HALVES == 2) ? (wv / WPG) : 0;
  int qh = q >> 1;
  float ga = 0.f, gb = 0.f;
#pragma unroll
  for (int w = 0; w < WPG; w++) {
    ga = fmaxf(ga, gmax[(half * WPG + w) * 4 + qh]);
    gb = fmaxf(gb, gmax[(half * WPG + w) * 4 + 2 + qh]);
  }
  float invA = (ga > 0.f) ? (127.0f / ga) : 0.f;
  float invB = (gb > 0.f) ? (127.0f / gb) : 0.f;
  // quantize acc directly -> byte stores (rows strided by 128B)
  signed char* qbase = (half ? qB : qA);
#pragma unroll
  for (int mt = 0; mt < MT; mt++) {
    float inv = mt ? invB : invA;
#pragma unroll
    for (int nt = 0; nt < NTW; nt++) {
      int colq = (wv * NTW + nt) * 16 + m - half * 128;
      signed char* dst = qbase + (size_t)(rowBase + mt * 16 + q * 4) * 128 + colq;
#pragma unroll
      for (int i = 0; i < 4; i++) {
        int qv = __float2int_rn(acc[mt][nt][i] * inv);
        dst[(size_t)i * 128] = (signed char)qv;
      }
    }
  }
}

// ---------------- bootstrap GEMM (stages both halves from global) ----------------

template <int NTW, int HALVES>
__global__ __launch_bounds__(512) void gemm_mfma_q(const unsigned short* __restrict__ A1,
                                                   const unsigned short* __restrict__ A2,
                                                   const unsigned short* __restrict__ Wp,
                                                   signed char* __restrict__ qA,
                                                   signed char* __restrict__ qB,
                                                   float* __restrict__ sA,
                                                   float* __restrict__ sB) {
  __shared__ unsigned short As[32 * 264];
  __shared__ float gmax[32];
  int rowBase = blockIdx.x * 32;
  int tid = threadIdx.x;
  for (int c = tid; c < 1024; c += 512) {
    int row = c >> 5; int rest = c & 31; int half = rest >> 4; int sub = rest & 15;
    const unsigned short* src = (half ? A2 : A1) + ((size_t)(rowBase + row) * 128 + sub * 8);
    *(uint4*)&As[row * 264 + half * 128 + sub * 8] = *(const uint4*)src;
  }
  __syncthreads();
  gemm_body<2, NTW, HALVES, 512>(As, gmax, Wp, qA, qB, sA, sB, rowBase, tid);
}

// ---------------- FUSED B/D: gates-gather prologue + candidate GEMM ----------------
// 8 gather units (4 nodes x {r,u}) -> one per wave. rh -> LDS A2; u -> global.
// A1 staged one-uint4-per-thread.

__global__ __launch_bounds__(512, 8) void fused_cand_q(
    const signed char* __restrict__ GqR, const signed char* __restrict__ GqU,
    const float* __restrict__ sR, const float* __restrict__ sU,
    const int* __restrict__ offs, const int* __restrict__ csr_src,
    const float* __restrict__ csr_w, const float* __restrict__ dis,
    const float* __restrict__ bRU, const unsigned short* __restrict__ h,
    unsigned short* __restrict__ u_out,
    const unsigned short* __restrict__ A1, const unsigned short* __restrict__ Wp,
    signed char* __restrict__ Cq, float* __restrict__ sC) {
  __shared__ unsigned short As[32 * 264];
  __shared__ float gmax[32];
  int tid = threadIdx.x;
  int wv = tid >> 6, lane = tid & 63;
  int rowBase = blockIdx.x * 32, gn0 = rowBase >> 3;
  int bb = lane >> 3, fo = (lane & 7) << 4;
  int node8 = wv >> 1, half = wv & 1;
  int n = gn0 + node8;
  int e0 = offs[n], e1 = offs[n + 1];   // metadata first (overlaps staging)
  // stage A1 (xin) into cols 0..127 — one uint4 per thread
  {
    int row = tid >> 4, sub = tid & 15;
    *(uint4*)&As[row * 264 + sub * 8] =
        *(const uint4*)&A1[(size_t)(rowBase + row) * 128 + sub * 8];
  }
  float acc[16];
  gather_accum(half ? GqU : GqR, half ? sU : sR, e0, e1, csr_src, csr_w, dis, n, bb, fo, acc);
  const float* bias = bRU + half * 128 + fo;
  size_t rowSelf = ((size_t)n << 3) + bb;
  if (half == 0) {
    int lr = node8 * 8 + bb;
#pragma unroll
    for (int jj = 0; jj < 2; jj++) {
      uint4 hq = *(const uint4*)&h[rowSelf * 128 + fo + 8 * jj];
      float hv[8];
      hv[0] = bflo(hq.x); hv[1] = bfhi(hq.x); hv[2] = bflo(hq.y); hv[3] = bfhi(hq.y);
      hv[4] = bflo(hq.z); hv[5] = bfhi(hq.z); hv[6] = bflo(hq.w); hv[7] = bfhi(hq.w);
      unsigned ow[4];
#pragma unroll
      for (int d = 0; d < 4; d++) {
        float s0 = 1.0f / (1.0f + __expf(-(acc[8 * jj + 2 * d]     + bias[8 * jj + 2 * d])));
        float s1 = 1.0f / (1.0f + __expf(-(acc[8 * jj + 2 * d + 1] + bias[8 * jj + 2 * d + 1])));
        ow[d] = (unsigned)f2bf(s0 * hv[2 * d]) | ((unsigned)f2bf(s1 * hv[2 * d + 1]) << 16);
      }
      uint4 o; o.x = ow[0]; o.y = ow[1]; o.z = ow[2]; o.w = ow[3];
      *(uint4*)&As[lr * 264 + 128 + fo + 8 * jj] = o;
    }
  } else {
#pragma unroll
    for (int jj = 0; jj < 2; jj++) {
      unsigned ow[4];
#pragma unroll
      for (int d = 0; d < 4; d++) {
        float s0 = 1.0f / (1.0f + __expf(-(acc[8 * jj + 2 * d]     + bias[8 * jj + 2 * d])));
        float s1 = 1.0f / (1.0f + __expf(-(acc[8 * jj + 2 * d + 1] + bias[8 * jj + 2 * d + 1])));
        ow[d] = (unsigned)f2bf(s0) | ((unsigned)f2bf(s1) << 16);
      }
      uint4 o; o.x = ow[0]; o.y = ow[1]; o.z = ow[2]; o.w = ow[3];
      *(uint4*)&u_out[rowSelf * 128 + fo + 8 * jj] = o;
    }
  }
  __syncthreads();
  gemm_body<2, 1, 1, 512>(As, gmax, Wp, Cq, Cq, sC, sC, rowBase, tid);
}

// ---------------- FUSED C: cand-gather + GRU prologue + gates GEMM ----------------
// Waves 0-3: full-degree cand-gather node wv, GRU (u from global) -> h + LDS A1.
// Waves 4-7: stage A2 (other layer's state).

__global__ __launch_bounds__(512, 8) void fused_gates_q(
    const signed char* __restrict__ Cq, const float* __restrict__ sC,
    const int* __restrict__ offs, const int* __restrict__ csr_src,
    const float* __restrict__ csr_w, const float* __restrict__ dis,
    const float* __restrict__ bC, const unsigned short* __restrict__ u_in,
    unsigned short* __restrict__ h_io,
    const unsigned short* __restrict__ A2src, const unsigned short* __restrict__ Wp,
    signed char* __restrict__ GqRo, signed char* __restrict__ GqUo,
    float* __restrict__ sRo, float* __restrict__ sUo) {
  __shared__ unsigned short As[32 * 264];
  __shared__ float gmax[32];
  int tid = threadIdx.x;
  int wv = tid >> 6, lane = tid & 63;
  int rowBase = blockIdx.x * 32, gn0 = rowBase >> 3;
  int bb = lane >> 3, fo = (lane & 7) << 4;
  if (wv >= 4) {
    int t2 = tid - 256;
    for (int c = t2; c < 512; c += 256) {
      int row = c >> 4, sub = c & 15;
      *(uint4*)&As[row * 264 + 128 + sub * 8] =
          *(const uint4*)&A2src[(size_t)(rowBase + row) * 128 + sub * 8];
    }
  } else {
    int node8 = wv;
    int n = gn0 + node8;
    int e0 = offs[n], e1 = offs[n + 1];
    float acc[16];
    gather_accum(Cq, sC, e0, e1, csr_src, csr_w, dis, n, bb, fo, acc);
    size_t rowSelf = ((size_t)n << 3) + bb;
    uint4 o0, o1;
    gru_combine_store(acc, bC + fo, u_in, h_io, rowSelf, fo, o0, o1);
    int lr = node8 * 8 + bb;
    *(uint4*)&As[lr * 264 + fo] = o0;
    *(uint4*)&As[lr * 264 + fo + 8] = o1;
  }
  __syncthreads();
  gemm_body<2, 2, 2, 512>(As, gmax, Wp, GqRo, GqUo, sRo, sUo, rowBase, tid);
}

// ---------------- FUSED E: cand-gather h1 GRU + lin_in(t+1) + gates0 GEMM ----------
// Waves 0-3: cand-gather node wv, GRU (u from global) -> h1 global.
// Waves 4-7: stage A2 (h0) + lin_in(t+1) -> LDS A1 + global xt.

__global__ __launch_bounds__(512, 8) void fused_gates_lin_q(
    const signed char* __restrict__ Cq, const float* __restrict__ sC,
    const int* __restrict__ offs, const int* __restrict__ csr_src,
    const float* __restrict__ csr_w, const float* __restrict__ dis,
    const float* __restrict__ bC, const unsigned short* __restrict__ u_in,
    unsigned short* __restrict__ h_io,
    const float* __restrict__ x_seq, const float* __restrict__ Win,
    const float* __restrict__ bin, unsigned short* __restrict__ xt_out,
    const unsigned short* __restrict__ A2src, const unsigned short* __restrict__ Wp,
    signed char* __restrict__ GqRo, signed char* __restrict__ GqUo,
    float* __restrict__ sRo, float* __restrict__ sUo, int t_next) {
  __shared__ unsigned short As[32 * 264];
  __shared__ float gmax[32];
  int tid = threadIdx.x;
  int wv = tid >> 6, lane = tid & 63;
  int rowBase = blockIdx.x * 32, gn0 = rowBase >> 3;
  int bb = lane >> 3, fo = (lane & 7) << 4;
  if (wv < 4) {
    int node8 = wv;
    int n = gn0 + node8;
    int e0 = offs[n], e1 = offs[n + 1];
    float acc[16];
    gather_accum(Cq, sC, e0, e1, csr_src, csr_w, dis, n, bb, fo, acc);
    size_t rowSelf = ((size_t)n << 3) + bb;
    uint4 o0, o1;
    gru_combine_store(acc, bC + fo, u_in, h_io, rowSelf, fo, o0, o1);
  } else {
    int t2 = tid - 256;
    // stage A2 (h0) into cols 128..255
    for (int c = t2; c < 512; c += 256) {
      int row = c >> 4, sub = c & 15;
      *(uint4*)&As[row * 264 + 128 + sub * 8] =
          *(const uint4*)&A2src[(size_t)(rowBase + row) * 128 + sub * 8];
    }
    // lin_in for t_next: 32 rows x 16 fh-units -> LDS cols 0..127 + global xt
    for (int c = t2; c < 512; c += 256) {
      int row = c >> 4, fh = c & 15;
      int grow = rowBase + row;
      int n2 = grow >> 3, bbv = grow & 7;
      const float* xp = x_seq + (((size_t)bbv * SS + t_next) * NN + n2) * FF;
      float4 a0 = *(const float4*)&bin[fh * 8];
      float4 a1 = *(const float4*)&bin[fh * 8 + 4];
#pragma unroll
      for (int ff = 0; ff < FF; ff++) {
        float xv = xp[ff];
        float4 w0 = *(const float4*)&Win[ff * HH + fh * 8];
        float4 w1 = *(const float4*)&Win[ff * HH + fh * 8 + 4];
        a0.x += xv * w0.x; a0.y += xv * w0.y; a0.z += xv * w0.z; a0.w += xv * w0.w;
        a1.x += xv * w1.x; a1.y += xv * w1.y; a1.z += xv * w1.z; a1.w += xv * w1.w;
      }
      uint4 o;
      o.x = (unsigned)f2bf(fmaxf(a0.x, 0.f)) | ((unsigned)f2bf(fmaxf(a0.y, 0.f)) << 16);
      o.y = (unsigned)f2bf(fmaxf(a0.z, 0.f)) | ((unsigned)f2bf(fmaxf(a0.w, 0.f)) << 16);
      o.z = (unsigned)f2bf(fmaxf(a1.x, 0.f)) | ((unsigned)f2bf(fmaxf(a1.y, 0.f)) << 16);
      o.w = (unsigned)f2bf(fmaxf(a1.z, 0.f)) | ((unsigned)f2bf(fmaxf(a1.w, 0.f)) << 16);
      *(uint4*)&As[row * 264 + fh * 8] = o;
      *(uint4*)&xt_out[(size_t)grow * 128 + fh * 8] = o;
    }
  }
  __syncthreads();
  gemm_body<2, 2, 2, 512>(As, gmax, Wp, GqRo, GqUo, sRo, sUo, rowBase, tid);
}

// ---------------- final candidate aggregation + GRU update (t = S-1, layer 1) --------

__global__ __launch_bounds__(256) void scatter_c_update_q(
    const signed char* __restrict__ Cq, const float* __restrict__ sC,
    const int* __restrict__ offs, const int* __restrict__ csr_src,
    const float* __restrict__ csr_w, const float* __restrict__ dis,
    const float* __restrict__ bC, const unsigned short* __restrict__ u,
    unsigned short* __restrict__ h) {
  int tid = threadIdx.x;
  int wv = tid >> 6, lane = tid & 63;
  int n = blockIdx.x * 4 + wv;
  int bb = lane >> 3;
  int fo = (lane & 7) << 4;
  int e0 = offs[n], e1 = offs[n + 1];
  float acc[16];
  gather_accum(Cq, sC, e0, e1, csr_src, csr_w, dis, n, bb, fo, acc);
  size_t rowSelf = (size_t)(n << 3) + bb;
  uint4 o0, o1;
  gru_combine_store(acc, bC + fo, u, h, rowSelf, fo, o0, o1);
}

// ---------------- BatchNorm stats ----------------

__global__ __launch_bounds__(256) void bn_stats_kernel(const unsigned short* __restrict__ h,
                                                       float* __restrict__ sums) {
  __shared__ float ls[512];
  int tid = threadIdx.x;
  float s = 0.f, sq = 0.f;
  for (size_t idx = (size_t)blockIdx.x * 256 + tid; idx < (size_t)TOTAL * HH;
       idx += (size_t)gridDim.x * 256) {
    float v = bf2f(h[idx]);
    s += v; sq += v * v;
  }
  ls[tid] = s; ls[256 + tid] = sq;
  __syncthreads();
  if (tid < 128) {
    atomicAdd(&sums[tid], ls[tid] + ls[tid + 128]);
    atomicAdd(&sums[128 + tid], ls[256 + tid] + ls[256 + tid + 128]);
  }
}

// ---------------- fused BN -> relu -> lin_out -> log_softmax ----------------

__global__ __launch_bounds__(256) void final_kernel(const unsigned short* __restrict__ h,
                                                    const float* __restrict__ sums,
                                                    const float* __restrict__ gamma,
                                                    const float* __restrict__ beta,
                                                    const float* __restrict__ Wout,
                                                    const float* __restrict__ bout,
                                                    float* __restrict__ out) {
  int wid = threadIdx.x >> 6, lane = threadIdx.x & 63;
  int row = blockIdx.x * 4 + wid; // node-row (n*8+bb order)
  if (row >= TOTAL) return;
  const float inv = 1.0f / (float)TOTAL;
  float p0 = 0.f, p1 = 0.f, p2 = 0.f, p3 = 0.f;
#pragma unroll
  for (int jj = 0; jj < 2; jj++) {
    int j = lane + jj * 64;
    float mean = sums[j] * inv;
    float var = sums[128 + j] * inv - mean * mean;
    float hn = (bf2f(h[(size_t)row * HH + j]) - mean) * rsqrtf(var + 1e-5f) * gamma[j] + beta[j];
    hn = fmaxf(hn, 0.0f);
    p0 += hn * Wout[j * 4 + 0];
    p1 += hn * Wout[j * 4 + 1];
    p2 += hn * Wout[j * 4 + 2];
    p3 += hn * Wout[j * 4 + 3];
  }
  for (int off = 32; off; off >>= 1) {
    p0 += __shfl_down(p0, off);
    p1 += __shfl_down(p1, off);
    p2 += __shfl_down(p2, off);
    p3 += __shfl_down(p3, off);
  }
  if (lane == 0) {
    p0 += bout[0]; p1 += bout[1]; p2 += bout[2]; p3 += bout[3];
    float m = fmaxf(fmaxf(p0, p1), fmaxf(p2, p3));
    float e = __expf(p0 - m) + __expf(p1 - m) + __expf(p2 - m) + __expf(p3 - m);
    float lse = m + __logf(e);
    int bb = row & 7, n = row >> 3;
    float* o = out + ((size_t)bb * NN + n) * 4;
    o[0] = p0 - lse; o[1] = p1 - lse; o[2] = p2 - lse; o[3] = p3 - lse;
  }
}

// ---------------- launcher ----------------

extern "C" void kernel_launch(void* const* d_in, const int* in_sizes, int n_in,
                              void* d_out, int out_size, void* d_ws, size_t ws_size,
                              hipStream_t stream) {
  const float* x_seq = (const float*)d_in[0];
  const int* ei      = (const int*)d_in[1];
  const float* ew    = (const float*)d_in[2];
  const float* Win   = (const float*)d_in[3];
  const float* bin   = (const float*)d_in[4];
  const float* convW = (const float*)d_in[5];
  const float* convB = (const float*)d_in[6];
  const float* gamma = (const float*)d_in[7];
  const float* beta  = (const float*)d_in[8];
  const float* Wout  = (const float*)d_in[9];
  const float* bout  = (const float*)d_in[10];
  float* out = (float*)d_out;

  char* ws = (char*)d_ws;
  size_t off = 0;
  auto alloc = [&](size_t bytes) {
    void* p = ws + off;
    off += (bytes + 1023) & ~(size_t)1023;
    return p;
  };
  float* deg     = (float*)alloc(NN * 4);
  float* dis     = (float*)alloc(NN * 4);
  int*   cnt     = (int*)alloc(NN * 4);
  int*   offs    = (int*)alloc((NN + 1) * 4);
  int*   cursor  = (int*)alloc(NN * 4);
  int*   csr_src = (int*)alloc(EE * 4);
  float* csr_w   = (float*)alloc(EE * 4);
  float* sums    = (float*)alloc(256 * 4);
  float* sR      = (float*)alloc(NN * 4);
  float* sU      = (float*)alloc(NN * 4);
  float* sC      = (float*)alloc(NN * 4);
  unsigned short* Wp = (unsigned short*)alloc(6 * 32768 * 2);  // packed conv weights
  const size_t NH = (size_t)TOTAL * HH; // 5,120,000
  unsigned short* h0 = (unsigned short*)alloc(NH * 2);
  unsigned short* h1 = (unsigned short*)alloc(NH * 2);
  unsigned short* xt = (unsigned short*)alloc(NH * 2);
  unsigned short* ub = (unsigned short*)alloc(NH * 2);
  signed char* GqR = (signed char*)alloc(NH);   // int8 messages
  signed char* GqU = (signed char*)alloc(NH);
  signed char* Cq  = (signed char*)alloc(NH);   // DEDICATED (no alias with GqR!)

  hipMemsetAsync(deg, 0, NN * 4, stream);
  hipMemsetAsync(cnt, 0, NN * 4, stream);
  hipMemsetAsync(cursor, 0, NN * 4, stream);
  hipMemsetAsync(sums, 0, 256 * 4, stream);
  hipMemsetAsync(h0, 0, NH * 2, stream);
  hipMemsetAsync(h1, 0, NH * 2, stream);

  deg_cnt_kernel<<<(EE + 255) / 256, 256, 0, stream>>>(ei, ew, deg, cnt);
  dis_kernel<<<(NN + 255) / 256, 256, 0, stream>>>(deg, dis);
  scan_kernel<<<1, 256, 0, stream>>>(cnt, offs);
  fill_csr_kernel<<<(EE + 255) / 256, 256, 0, stream>>>(ei, ew, dis, offs, cursor, csr_src, csr_w);
  prepack_kernel<<<24576 / 256, 256, 0, stream>>>(convW, Wp);

  const unsigned short* Wg0 = Wp;
  const unsigned short* Wc0 = Wp + (size_t)2 * 32768;
  const unsigned short* Wg1 = Wp + (size_t)3 * 32768;
  const unsigned short* Wc1 = Wp + (size_t)5 * 32768;
  const float* bRU0 = convB;
  const float* bC0  = convB + 2 * HH;
  const float* bRU1 = convB + 3 * HH;
  const float* bC1  = convB + 5 * HH;

  // bootstrap: xt(t=0), gates0(t=0)
  lin_in_kernel<<<TOTAL * 16 / 256, 256, 0, stream>>>(x_seq, Win, bin, xt, 0);
  gemm_mfma_q<2, 2><<<TOTAL / 32, 512, 0, stream>>>(xt, h0, Wg0, GqR, GqU, sR, sU);

  for (int t = 0; t < SS; t++) {
    // B: gates0-gather -> rh0(LDS), u0 -> cand0 GEMM -> Cq
    fused_cand_q<<<TOTAL / 32, 512, 0, stream>>>(GqR, GqU, sR, sU, offs, csr_src, csr_w,
                                                 dis, bRU0, h0, ub, xt, Wc0, Cq, sC);
    // C: cand0-gather -> h0 update (global+LDS A1) -> gates1 GEMM -> GqR/GqU
    fused_gates_q<<<TOTAL / 32, 512, 0, stream>>>(Cq, sC, offs, csr_src, csr_w, dis,
                                                  bC0, ub, h0, h1, Wg1, GqR, GqU, sR, sU);
    // D: gates1-gather -> rh1(LDS), u1 -> cand1 GEMM -> Cq
    fused_cand_q<<<TOTAL / 32, 512, 0, stream>>>(GqR, GqU, sR, sU, offs, csr_src, csr_w,
                                                 dis, bRU1, h1, ub, h0, Wc1, Cq, sC);
    // E: cand1-gather -> h1 update; lin_in(t+1) -> xt; gates0 GEMM -> GqR/GqU
    if (t < SS - 1) {
      fused_gates_lin_q<<<TOTAL / 32, 512, 0, stream>>>(Cq, sC, offs, csr_src, csr_w, dis,
                                                        bC1, ub, h1, x_seq, Win, bin, xt,
                                                        h0, Wg0, GqR, GqU, sR, sU, t + 1);
    } else {
      scatter_c_update_q<<<NN / 4, 256, 0, stream>>>(Cq, sC, offs, csr_src, csr_w,
                                                     dis, bC1, ub, h1);
    }
  }

  bn_stats_kernel<<<256, 256, 0, stream>>>(h1, sums);
  final_kernel<<<TOTAL / 4, 256, 0, stream>>>(h1, sums, gamma, beta, Wout, bout, out);
}